// Round 7
// baseline (589.967 us; speedup 1.0000x reference)
//
#include <hip/hip_runtime.h>
#include <cmath>

struct K32 { float k[32]; };
struct K16 { float k[16]; };

#define THETA 10.0f

// ====== L1 FULLY FUSED (R5-proven, R6 skip REVERTED): conv1(raw x) + psp1 +
//        spike1 + psp2 + pool1 + spike2  ->  s2  ======
template <int CIN, int COUT, int KK, int HIN, int WIN, int S1H, int S1W,
          int S2H, int S2W>
__global__ __launch_bounds__(256)
void conv_pps_kernel(const float* __restrict__ x, const float* __restrict__ w,
                     float* __restrict__ s2out, K32 pk, K16 rk) {
  constexpr int WT = 4;                       // s1-wo per wave
  constexpr int SW = 8;                       // s1-wo per block
  constexpr int XR = 2 * (WT - 1) + KK;       // 11
  constexpr int GROUPS = (S1W + SW - 1) / SW; // 16
  constexpr int NROW = COUT * 2 * SW;         // 128
  constexpr int T0 = 39;                      // balanced part split
  __shared__ float lds[NROW * 51];            // 26 KB
  const int tid = threadIdx.x;
  const int wave = tid >> 6;
  const int lane = tid & 63;
  const int group = blockIdx.x % GROUPS;
  const int rest = blockIdx.x / GROUPS;
  const int hop = rest % S2H;                 // s2 ho
  const int n = rest / S2H;
  const int ho_off = wave & 1;
  const int wo_half = wave >> 1;
  const int ho = 2 * hop + ho_off;            // s1 ho
  const int wo0 = group * SW + wo_half * WT;
  const int tt = lane < 50 ? lane : 49;

  // ---- conv on RAW binary spikes (proven order c -> kh -> co -> kw -> wl) ----
  float acc[COUT][WT] = {};
  for (int c = 0; c < CIN; ++c) {
#pragma unroll
    for (int kh = 0; kh < KK; ++kh) {
      const int hi = 2 * ho + kh - 1;
      if ((unsigned)hi >= (unsigned)HIN) continue;   // zero padding
      float xr[XR];
#pragma unroll
      for (int i = 0; i < XR; ++i) {
        const int wi = 2 * wo0 - 1 + i;
        xr[i] = ((unsigned)wi < (unsigned)WIN)
                    ? x[(((size_t)(n * CIN + c) * HIN + hi) * WIN + wi) * 50 + tt]
                    : 0.f;
      }
#pragma unroll
      for (int co = 0; co < COUT; ++co)
#pragma unroll
        for (int kw = 0; kw < KK; ++kw) {
          const float wv = w[((co * CIN + c) * KK + kh) * KK + kw];
#pragma unroll
          for (int wl = 0; wl < WT; ++wl)
            acc[co][wl] += xr[2 * wl + kw] * wv;
        }
    }
  }
  // ---- transpose: LDS row = co*16 + ho_off*8 + wol ----
  if (lane < 50) {
#pragma unroll
    for (int co = 0; co < COUT; ++co)
#pragma unroll
      for (int wl = 0; wl < WT; ++wl)
        lds[((co * 2 + ho_off) * SW + wo_half * WT + wl) * 51 + lane] = acc[co][wl];
  }
  __syncthreads();
  // ---- FUSED FIR1(psp1) + spike1 + FIR2(psp2): 2 threads/row, registers ----
  {
    const int r = tid & (NROW - 1);
    const int part = tid >> 7;                // 0: y[0..T0), 1: y[T0..49]
    const int wol = r & (SW - 1);
    const bool act = (group * SW + wol) < S1W;
    float xs[50];                             // conv output c
    if (act) {
      if (part == 0) {
#pragma unroll
        for (int t = 0; t < T0; ++t) xs[t] = lds[r * 51 + t];
      } else {
#pragma unroll
        for (int t = 0; t < 50; ++t) xs[t] = lds[r * 51 + t];
      }
    }
    __syncthreads();                          // all reads done before any FIR write
    if (act) {
      if (part == 0) {
        float us[T0];
#pragma unroll
        for (int t = 0; t < 32; ++t) {        // FIR1: u[0..31] (guarded taps)
          float a = 0.f;
#pragma unroll
          for (int k = 31; k >= 0; --k)
            if (t - k >= 0) a += xs[t - k] * pk.k[k];
          us[t] = a;
        }
#pragma unroll
        for (int t = 32; t < T0; ++t) {       // FIR1: u[32..38] (all taps valid)
          float a = 0.f;
#pragma unroll
          for (int k = 31; k >= 0; --k)
            a += xs[t - k] * pk.k[k];
          us[t] = a;
        }
        float buf[16];
#pragma unroll
        for (int j = 0; j < 16; ++j) buf[j] = 0.f;
#pragma unroll
        for (int t = 0; t < T0; ++t) {        // spike1 in regs, overwrite us
          float v = us[t] + buf[t & 15];
          buf[t & 15] = 0.f;
          float sp = 0.f;
          if (v >= THETA) {
            sp = 1.f;
#pragma unroll
            for (int j = 0; j < 16; ++j) buf[(t + 1 + j) & 15] += rk.k[j];
          }
          us[t] = sp;
        }
#pragma unroll
        for (int t = 0; t < 32; ++t) {        // FIR2: y[0..31] (guarded)
          float a = 0.f;
#pragma unroll
          for (int k = 31; k >= 0; --k)
            if (t - k >= 0) a += us[t - k] * pk.k[k];
          lds[r * 51 + t] = a;
        }
#pragma unroll
        for (int t = 32; t < T0; ++t) {       // FIR2: y[32..38] (all taps valid)
          float a = 0.f;
#pragma unroll
          for (int k = 31; k >= 0; --k)
            a += us[t - k] * pk.k[k];
          lds[r * 51 + t] = a;
        }
      } else {
        float us[50];
#pragma unroll
        for (int t = 0; t < 32; ++t) {        // FIR1 full prefix (guarded)
          float a = 0.f;
#pragma unroll
          for (int k = 31; k >= 0; --k)
            if (t - k >= 0) a += xs[t - k] * pk.k[k];
          us[t] = a;
        }
#pragma unroll
        for (int t = 32; t < 50; ++t) {       // FIR1 (all taps valid)
          float a = 0.f;
#pragma unroll
          for (int k = 31; k >= 0; --k)
            a += xs[t - k] * pk.k[k];
          us[t] = a;
        }
        float buf[16];
#pragma unroll
        for (int j = 0; j < 16; ++j) buf[j] = 0.f;
#pragma unroll
        for (int t = 0; t < 50; ++t) {        // spike1 full row, overwrite us
          float v = us[t] + buf[t & 15];
          buf[t & 15] = 0.f;
          float sp = 0.f;
          if (v >= THETA) {
            sp = 1.f;
#pragma unroll
            for (int j = 0; j < 16; ++j) buf[(t + 1 + j) & 15] += rk.k[j];
          }
          us[t] = sp;
        }
#pragma unroll
        for (int t = T0; t < 50; ++t) {       // FIR2: y[39..49] (all taps valid)
          float a = 0.f;
#pragma unroll
          for (int k = 31; k >= 0; --k)
            a += us[t - k] * pk.k[k];
          lds[r * 51 + t] = a;
        }
      }
    }
  }
  __syncthreads();
  // ---- pool ((h0w0+h0w1)+h1w0)+h1w1 * 2.75 -> spike -> direct store ----
  if (tid < COUT * (SW / 2)) {                // 32 threads
    const int co = tid / (SW / 2);
    const int wpl = tid % (SW / 2);
    const int wop = group * (SW / 2) + wpl;   // s2 wo
    if (wop < S2W) {
      const int r00 = (co * 16 + 2 * wpl) * 51;
      const int r01 = (co * 16 + 2 * wpl + 1) * 51;
      const int r10 = (co * 16 + 8 + 2 * wpl) * 51;
      const int r11 = (co * 16 + 8 + 2 * wpl + 1) * 51;
      float* orow = s2out + (((size_t)(n * COUT + co) * S2H + hop) * S2W + wop) * 50;
      float buf[16];
#pragma unroll
      for (int j = 0; j < 16; ++j) buf[j] = 0.f;
      float prev = 0.f;
#pragma unroll
      for (int t = 0; t < 50; ++t) {
        const float u0 = (((lds[r00 + t] + lds[r01 + t]) + lds[r10 + t]) + lds[r11 + t]) * 2.75f;
        float v = u0 + buf[t & 15];
        buf[t & 15] = 0.f;
        float sp = 0.f;
        if (v >= THETA) {
          sp = 1.f;
#pragma unroll
          for (int j = 0; j < 16; ++j) buf[(t + 1 + j) & 15] += rk.k[j];
        }
        if (t & 1) *(float2*)(orow + t - 1) = make_float2(prev, sp);
        else prev = sp;
      }
    }
  }
}

// ====== L2 MERGED (R4-proven + R6 sparse-skip KEPT for A/B): conv2 + psp3 +
//        spike3 + pool2 + psp4 + spike4 ======
template <int CIN, int COUT, int KK, int SW, int WT, int HIN, int WIN,
          int S1H, int S1W, int S2H, int S2W>
__global__ __launch_bounds__(256)
void conv_pps2_kernel(const float* __restrict__ x, const float* __restrict__ w,
                      float* __restrict__ s2out, K32 pk, K16 rk) {
  constexpr int XR = 2 * (WT - 1) + KK;       // 5
  constexpr int GROUPS = (S1W + SW - 1) / SW; // 8
  constexpr int NROW = COUT * 2 * SW;         // 128
  constexpr int NROWP = COUT * (SW / 2);      // 32 pooled rows
  __shared__ float lds[NROW * 51];            // 26 KB
  const int tid = threadIdx.x;
  const int wave = tid >> 6;
  const int lane = tid & 63;
  const int group = blockIdx.x % GROUPS;
  const int rest = blockIdx.x / GROUPS;
  const int hop = rest % S2H;                 // s2 ho
  const int n = rest / S2H;
  const int ho_off = wave & 1;
  const int wo_half = wave >> 1;
  const int ho = 2 * hop + ho_off;            // s1 ho
  const int wo0 = group * SW + wo_half * WT;
  const int tt = lane < 50 ? lane : 49;

  // ---- conv on raw s2 spikes, i-major with sparsity skip ----
  float acc[COUT][WT] = {};
  for (int c = 0; c < CIN; ++c) {
#pragma unroll
    for (int kh = 0; kh < KK; ++kh) {
      const int hi = 2 * ho + kh - 1;
      if ((unsigned)hi >= (unsigned)HIN) continue;   // zero padding
      float xr[XR];
#pragma unroll
      for (int i = 0; i < XR; ++i) {
        const int wi = 2 * wo0 - 1 + i;
        xr[i] = ((unsigned)wi < (unsigned)WIN)
                    ? x[(((size_t)(n * CIN + c) * HIN + hi) * WIN + wi) * 50 + tt]
                    : 0.f;
      }
#pragma unroll
      for (int i = 0; i < XR; ++i) {
        if (__any(xr[i] != 0.f)) {
#pragma unroll
          for (int co = 0; co < COUT; ++co)
#pragma unroll
            for (int wl = 0; wl < WT; ++wl)
#pragma unroll
              for (int kw = 0; kw < KK; ++kw)
                if (2 * wl + kw == i)          // compile-time after unroll
                  acc[co][wl] += xr[i] * w[((co * CIN + c) * KK + kh) * KK + kw];
        }
      }
    }
  }
  // ---- transpose: LDS row = (co*2 + ho_off)*SW + wol ----
  if (lane < 50) {
#pragma unroll
    for (int co = 0; co < COUT; ++co)
#pragma unroll
      for (int wl = 0; wl < WT; ++wl)
        lds[((co * 2 + ho_off) * SW + wo_half * WT + wl) * 51 + lane] = acc[co][wl];
  }
  __syncthreads();
  // ---- FIR (psp3) on 128 conv rows: 2 thr/row, snapshot -> barrier -> in-place ----
  {
    const int r = tid & (NROW - 1);
    const int part = tid >> 7;                // 0: y[0..31], 1: y[32..49]
    float xs[50];
    if (part == 0) {
#pragma unroll
      for (int t = 0; t < 32; ++t) xs[t] = lds[r * 51 + t];
    } else {
#pragma unroll
      for (int t = 0; t < 50; ++t) xs[t] = lds[r * 51 + t];
    }
    __syncthreads();
    if (part == 0) {
#pragma unroll
      for (int t = 0; t < 32; ++t) {
        float a = 0.f;
#pragma unroll
        for (int k = 31; k >= 0; --k)
          if (t - k >= 0) a += xs[t - k] * pk.k[k];
        lds[r * 51 + t] = a;
      }
    } else {
#pragma unroll
      for (int t = 32; t < 50; ++t) {
        float a = 0.f;
#pragma unroll
        for (int k = 31; k >= 0; --k)
          a += xs[t - k] * pk.k[k];            // all taps valid for t >= 32
        lds[r * 51 + t] = a;
      }
    }
  }
  __syncthreads();
  // ---- spike3 per row (128 rows, in place) ----
  if (tid < NROW) {
    float buf[16];
#pragma unroll
    for (int j = 0; j < 16; ++j) buf[j] = 0.f;
#pragma unroll
    for (int t = 0; t < 50; ++t) {
      float v = lds[tid * 51 + t] + buf[t & 15];
      buf[t & 15] = 0.f;
      float sp = 0.f;
      if (v >= THETA) {
        sp = 1.f;
#pragma unroll
        for (int j = 0; j < 16; ++j) buf[(t + 1 + j) & 15] += rk.k[j];
      }
      lds[tid * 51 + t] = sp;
    }
  }
  __syncthreads();
  // ---- pool-sum + FIR (psp4) on 32 pooled rows: 2 thr/row ----
  {
    const int r = tid & (NROWP - 1);
    const int part = tid >> 5;                // 0..7, only part<2 active
    const bool act = part < 2;
    const int co = r / (SW / 2);
    const int wpl = r % (SW / 2);
    const int r00 = ((co * 2) * SW + 2 * wpl) * 51;
    const int r01 = r00 + 51;
    const int r10 = ((co * 2 + 1) * SW + 2 * wpl) * 51;
    const int r11 = r10 + 51;
    float xs[50];
    if (act) {
      if (part == 0) {
#pragma unroll
        for (int t = 0; t < 32; ++t)
          xs[t] = (((lds[r00 + t] + lds[r01 + t]) + lds[r10 + t]) + lds[r11 + t]) * 2.75f;
      } else {
#pragma unroll
        for (int t = 0; t < 50; ++t)
          xs[t] = (((lds[r00 + t] + lds[r01 + t]) + lds[r10 + t]) + lds[r11 + t]) * 2.75f;
      }
    }
    __syncthreads();
    if (act) {
      if (part == 0) {
#pragma unroll
        for (int t = 0; t < 32; ++t) {
          float a = 0.f;
#pragma unroll
          for (int k = 31; k >= 0; --k)
            if (t - k >= 0) a += xs[t - k] * pk.k[k];
          lds[r00 + t] = a;
        }
      } else {
#pragma unroll
        for (int t = 32; t < 50; ++t) {
          float a = 0.f;
#pragma unroll
          for (int k = 31; k >= 0; --k)
            a += xs[t - k] * pk.k[k];
          lds[r00 + t] = a;
        }
      }
    }
  }
  __syncthreads();
  // ---- spike4 -> direct store ----
  if (tid < NROWP) {
    const int co = tid / (SW / 2);
    const int wpl = tid % (SW / 2);
    const int wop = group * (SW / 2) + wpl;   // s2 wo
    if (wop < S2W) {
      const int r00 = ((co * 2) * SW + 2 * wpl) * 51;
      float* orow = s2out + (((size_t)(n * COUT + co) * S2H + hop) * S2W + wop) * 50;
      float buf[16];
#pragma unroll
      for (int j = 0; j < 16; ++j) buf[j] = 0.f;
      float prev = 0.f;
#pragma unroll
      for (int t = 0; t < 50; ++t) {
        float v = lds[r00 + t] + buf[t & 15];
        buf[t & 15] = 0.f;
        float sp = 0.f;
        if (v >= THETA) {
          sp = 1.f;
#pragma unroll
          for (int j = 0; j < 16; ++j) buf[(t + 1 + j) & 15] += rk.k[j];
        }
        if (t & 1) *(float2*)(orow + t - 1) = make_float2(prev, sp);
        else prev = sp;
      }
    }
  }
}

// ====== fused conv (stride2,pad1) + psp(commuted) + spike (verified, L3 only) ======
template <int CIN, int COUT, int KK, int WT, int HIN, int WIN, int HOUT, int WOUT>
__global__ __launch_bounds__(256)
void conv_fir_spike_kernel(const float* __restrict__ x, const float* __restrict__ w,
                           float* __restrict__ s, K32 pk, K16 rk) {
  constexpr int XR = 2 * (WT - 1) + KK;
  constexpr int TW = 4 * WT;                 // wo span per block (4 waves)
  constexpr int GROUPS = (WOUT + TW - 1) / TW;
  constexpr int NROW = COUT * TW;
  __shared__ float lds[NROW * 51];
  const int tid = threadIdx.x;
  const int wave = tid >> 6;
  const int lane = tid & 63;
  const int group = blockIdx.x % GROUPS;
  const int rest = blockIdx.x / GROUPS;
  const int ho = rest % HOUT;
  const int n = rest / HOUT;
  const int wo0 = group * TW + wave * WT;
  const int tt = lane < 50 ? lane : 49;

  float acc[COUT][WT] = {};
  for (int c = 0; c < CIN; ++c) {
#pragma unroll
    for (int kh = 0; kh < KK; ++kh) {
      const int hi = 2 * ho + kh - 1;
      if ((unsigned)hi >= (unsigned)HIN) continue;   // zero padding
      float xr[XR];
#pragma unroll
      for (int i = 0; i < XR; ++i) {
        const int wi = 2 * wo0 - 1 + i;
        xr[i] = ((unsigned)wi < (unsigned)WIN)
                    ? x[(((size_t)(n * CIN + c) * HIN + hi) * WIN + wi) * 50 + tt]
                    : 0.f;
      }
#pragma unroll
      for (int co = 0; co < COUT; ++co)
#pragma unroll
        for (int kw = 0; kw < KK; ++kw) {
          const float wv = w[((co * CIN + c) * KK + kh) * KK + kw];
#pragma unroll
          for (int wl = 0; wl < WT; ++wl)
            acc[co][wl] += xr[2 * wl + kw] * wv;
        }
    }
  }

  if (lane < 50) {
#pragma unroll
    for (int co = 0; co < COUT; ++co)
#pragma unroll
      for (int wl = 0; wl < WT; ++wl)
        lds[(co * TW + wave * WT + wl) * 51 + lane] = acc[co][wl];
  }
  __syncthreads();
  // ---- FIR = psp (commuted past conv): 2 threads/row ----
  {
    const int r = tid % NROW;
    const int part = tid / NROW;
    const int wol = r % TW;
    const bool act = (part < 2) && (group * TW + wol < WOUT);
    float xs[50];
    if (act) {
      if (part == 0) {
#pragma unroll
        for (int t = 0; t < 25; ++t) xs[t] = lds[r * 51 + t];
      } else {
#pragma unroll
        for (int t = 0; t < 50; ++t) xs[t] = lds[r * 51 + t];
      }
    }
    __syncthreads();
    if (act) {
      if (part == 0) {
#pragma unroll
        for (int t = 0; t < 25; ++t) {
          float a = 0.f;
#pragma unroll
          for (int k = 31; k >= 0; --k)
            if (t - k >= 0) a += xs[t - k] * pk.k[k];
          lds[r * 51 + t] = a;
        }
      } else {
#pragma unroll
        for (int t = 25; t < 50; ++t) {
          float a = 0.f;
#pragma unroll
          for (int k = 31; k >= 0; --k)
            if (t - k >= 0) a += xs[t - k] * pk.k[k];
          lds[r * 51 + t] = a;
        }
      }
    }
  }
  __syncthreads();
  // spike along t, one thread per output row, direct float2 store from regs
  if (tid < NROW) {
    const int co = tid / TW;
    const int wol = tid - co * TW;
    const int wo = group * TW + wol;
    if (wo < WOUT) {
      float* orow = s + (((size_t)(n * COUT + co) * HOUT + ho) * WOUT + wo) * 50;
      float buf[16];
#pragma unroll
      for (int j = 0; j < 16; ++j) buf[j] = 0.f;
      float prev = 0.f;
#pragma unroll
      for (int t = 0; t < 50; ++t) {
        float v = lds[tid * 51 + t] + buf[t & 15];
        buf[t & 15] = 0.f;
        float sp = 0.f;
        if (v >= THETA) {
          sp = 1.f;
#pragma unroll
          for (int j = 0; j < 16; ++j) buf[(t + 1 + j) & 15] += rk.k[j];
        }
        if (t & 1) *(float2*)(orow + t - 1) = make_float2(prev, sp);
        else prev = sp;
      }
    }
  }
}

// ====== fc + psp(commuted) + final spike (verified) ======
__global__ __launch_bounds__(512)
void fc_fir_spike_kernel(const float* __restrict__ w, const float* __restrict__ s,
                         float* __restrict__ out, K32 pk, K16 rk) {
  __shared__ float lds[8 * 51];
  const int tid = threadIdx.x;
  const int wave = tid >> 6, lane = tid & 63;
  const int o = wave & 1, n = wave >> 1;
  const int tt = lane < 50 ? lane : 49;
  const float* wrow = w + (size_t)o * 2048;
  const float* ub = s + (size_t)n * 2048 * 50;
  float acc = 0.f;
#pragma unroll 32
  for (int i = 0; i < 2048; ++i) acc += wrow[i] * ub[(size_t)i * 50 + tt];
  if (lane < 50) lds[wave * 51 + lane] = acc;
  __syncthreads();
  // ---- FIR = psp6 (commuted past einsum): 2 threads/row, in place ----
  {
    const int r = tid & 7;
    const int part = tid >> 3;      // only part<2 active
    const bool act = part < 2;
    float xs[50];
    if (act) {
      if (part == 0) {
#pragma unroll
        for (int t = 0; t < 25; ++t) xs[t] = lds[r * 51 + t];
      } else {
#pragma unroll
        for (int t = 0; t < 50; ++t) xs[t] = lds[r * 51 + t];
      }
    }
    __syncthreads();
    if (act) {
      if (part == 0) {
#pragma unroll
        for (int t = 0; t < 25; ++t) {
          float a = 0.f;
#pragma unroll
          for (int k = 31; k >= 0; --k)
            if (t - k >= 0) a += xs[t - k] * pk.k[k];
          lds[r * 51 + t] = a;
        }
      } else {
#pragma unroll
        for (int t = 25; t < 50; ++t) {
          float a = 0.f;
#pragma unroll
          for (int k = 31; k >= 0; --k)
            if (t - k >= 0) a += xs[t - k] * pk.k[k];
          lds[r * 51 + t] = a;
        }
      }
    }
  }
  __syncthreads();
  if (tid < 8) {
    float buf[16];
#pragma unroll
    for (int j = 0; j < 16; ++j) buf[j] = 0.f;
#pragma unroll
    for (int t = 0; t < 50; ++t) {
      float v = lds[tid * 51 + t] + buf[t & 15];
      buf[t & 15] = 0.f;
      float sp = 0.f;
      if (v >= THETA) {
        sp = 1.f;
#pragma unroll
        for (int j = 0; j < 16; ++j) buf[(t + 1 + j) & 15] += rk.k[j];
      }
      out[tid * 50 + t] = sp;
    }
  }
}

extern "C" void kernel_launch(void* const* d_in, const int* in_sizes, int n_in,
                              void* d_out, int out_size, void* d_ws, size_t ws_size,
                              hipStream_t stream) {
  const float* xin = (const float*)d_in[0];  // [4,2,256,256,50] raw binary spikes
  const float* w1  = (const float*)d_in[1];  // [8,2,5,5]
  const float* w2  = (const float*)d_in[2];  // [16,8,3,3]
  const float* w3  = (const float*)d_in[3];  // [32,16,3,3]
  const float* wfc = (const float*)d_in[4];  // [2,32,8,8]
  float* out = (float*)d_out;                // [4,2,1,1,50]

  float* R0 = (float*)d_ws;                  // 26,214,400 floats
  float* R1 = R0 + 26214400;

  K32 pk;
  for (int k = 0; k < 32; ++k)
    pk.k[k] = (float)(((double)k / 10.0) * exp(1.0 - (double)k / 10.0));
  K16 rk;
  for (int j = 0; j < 16; ++j) {
    const double tr = (double)(j + 1);
    rk.k[j] = (float)(-2.0 * 10.0 * tr * exp(1.0 - tr));
  }

  // 1. FULLY FUSED L1: conv1(raw x)+psp1+spike1+psp2+pool1+spike2: xin -> R1 = s2
  conv_pps_kernel<2, 8, 5, 256, 256, 127, 127, 63, 63>
      <<<4 * 63 * 16, 256, 0, stream>>>(xin, w1, R1, pk, rk);
  // 2. MERGED L2: conv2+psp3+spike3+pool2+psp4+spike4: R1 -> R0 = s4 [4,16,16,16,50]
  conv_pps2_kernel<8, 16, 3, 4, 2, 63, 63, 32, 32, 16, 16>
      <<<4 * 16 * 8, 256, 0, stream>>>(R1, w2, R0, pk, rk);
  // 3. FUSED conv3+psp5+spike5: R0 -> R1 = s5 [4,32,8,8,50]
  conv_fir_spike_kernel<16, 32, 3, 1, 16, 16, 8, 8>
      <<<4 * 8 * 2, 256, 0, stream>>>(R0, w3, R1, pk, rk);
  // 4. FUSED fc+psp6+final spike: R1 -> out
  fc_fir_spike_kernel<<<1, 512, 0, stream>>>(wfc, R1, out, pk, rk);
}

// Round 8
// 589.217 us; speedup vs baseline: 1.0013x; 1.0013x over previous
//
#include <hip/hip_runtime.h>
#include <cmath>

struct K32 { float k[32]; };
struct K16 { float k[16]; };

#define THETA 10.0f

// ====== L1 FULLY FUSED (R8): conv1(raw x) + psp1 + spike1 + psp2 + pool1 +
//        spike2 -> s2.  R8: FIR phase split-pipelined at T=32 via spike-bit
//        relay (part0 publishes 32 spike bits in LDS col 50; part1 resumes
//        the spike chain from reconstructed refractory state). Removes
//        part1's duplicated FIR1-prefix + spike-prefix (-26% phase work).
template <int CIN, int COUT, int KK, int HIN, int WIN, int S1H, int S1W,
          int S2H, int S2W>
__global__ __launch_bounds__(256)
void conv_pps_kernel(const float* __restrict__ x, const float* __restrict__ w,
                     float* __restrict__ s2out, K32 pk, K16 rk) {
  constexpr int WT = 4;                       // s1-wo per wave
  constexpr int SW = 8;                       // s1-wo per block
  constexpr int XR = 2 * (WT - 1) + KK;       // 11
  constexpr int GROUPS = (S1W + SW - 1) / SW; // 16
  constexpr int NROW = COUT * 2 * SW;         // 128
  __shared__ float lds[NROW * 51];            // 26 KB (col 50 = spike-bit relay)
  const int tid = threadIdx.x;
  const int wave = tid >> 6;
  const int lane = tid & 63;
  const int group = blockIdx.x % GROUPS;
  const int rest = blockIdx.x / GROUPS;
  const int hop = rest % S2H;                 // s2 ho
  const int n = rest / S2H;
  const int ho_off = wave & 1;
  const int wo_half = wave >> 1;
  const int ho = 2 * hop + ho_off;            // s1 ho
  const int wo0 = group * SW + wo_half * WT;
  const int tt = lane < 50 ? lane : 49;

  // ---- conv on RAW binary spikes (proven order c -> kh -> co -> kw -> wl) ----
  float acc[COUT][WT] = {};
  for (int c = 0; c < CIN; ++c) {
#pragma unroll
    for (int kh = 0; kh < KK; ++kh) {
      const int hi = 2 * ho + kh - 1;
      if ((unsigned)hi >= (unsigned)HIN) continue;   // zero padding
      float xr[XR];
#pragma unroll
      for (int i = 0; i < XR; ++i) {
        const int wi = 2 * wo0 - 1 + i;
        xr[i] = ((unsigned)wi < (unsigned)WIN)
                    ? x[(((size_t)(n * CIN + c) * HIN + hi) * WIN + wi) * 50 + tt]
                    : 0.f;
      }
#pragma unroll
      for (int co = 0; co < COUT; ++co)
#pragma unroll
        for (int kw = 0; kw < KK; ++kw) {
          const float wv = w[((co * CIN + c) * KK + kh) * KK + kw];
#pragma unroll
          for (int wl = 0; wl < WT; ++wl)
            acc[co][wl] += xr[2 * wl + kw] * wv;
        }
    }
  }
  // ---- transpose: LDS row = co*16 + ho_off*8 + wol ----
  if (lane < 50) {
#pragma unroll
    for (int co = 0; co < COUT; ++co)
#pragma unroll
      for (int wl = 0; wl < WT; ++wl)
        lds[((co * 2 + ho_off) * SW + wo_half * WT + wl) * 51 + lane] = acc[co][wl];
  }
  __syncthreads();
  // ---- FUSED FIR1(psp1)+spike1+FIR2(psp2), split-pipelined at T=32 ----
  {
    const int r = tid & (NROW - 1);
    const int part = tid >> 7;                // 0: t<32, 1: t>=32
    const int wol = r & (SW - 1);
    const bool act = (group * SW + wol) < S1W;
    float xs[50];                             // conv output u-candidates
    if (act) {
      if (part == 0) {
#pragma unroll
        for (int t = 0; t < 32; ++t) xs[t] = lds[r * 51 + t];
      } else {
#pragma unroll
        for (int t = 0; t < 50; ++t) xs[t] = lds[r * 51 + t];
      }
    }
    __syncthreads();                          // snapshot done before any write
    float s0[32];                             // part0: u then spike prefix
    float u1[18];                             // part1: FIR1 outputs t in [32,50)
    if (act) {
      if (part == 0) {
        // FIR1 guarded, t<32 (identical arithmetic to proven prefix)
#pragma unroll
        for (int t = 0; t < 32; ++t) {
          float a = 0.f;
#pragma unroll
          for (int k = 31; k >= 0; --k)
            if (t - k >= 0) a += xs[t - k] * pk.k[k];
          s0[t] = a;
        }
        // spike prefix in regs; pack bits
        float buf[16];
#pragma unroll
        for (int j = 0; j < 16; ++j) buf[j] = 0.f;
        unsigned bits = 0u;
#pragma unroll
        for (int t = 0; t < 32; ++t) {
          float v = s0[t] + buf[t & 15];
          buf[t & 15] = 0.f;
          float sp = 0.f;
          if (v >= THETA) {
            sp = 1.f;
            bits |= (1u << t);
#pragma unroll
            for (int j = 0; j < 16; ++j) buf[(t + 1 + j) & 15] += rk.k[j];
          }
          s0[t] = sp;
        }
        lds[r * 51 + 50] = __uint_as_float(bits);   // relay spike prefix
      } else {
        // FIR1 unguarded, t in [32,50) (all 32 taps valid)
#pragma unroll
        for (int t = 32; t < 50; ++t) {
          float a = 0.f;
#pragma unroll
          for (int k = 31; k >= 0; --k)
            a += xs[t - k] * pk.k[k];
          u1[t - 32] = a;
        }
      }
    }
    __syncthreads();                          // publish bits before part1 reads
    if (act) {
      if (part == 0) {
        // FIR2 guarded, t<32, from own spike prefix
#pragma unroll
        for (int t = 0; t < 32; ++t) {
          float a = 0.f;
#pragma unroll
          for (int k = 31; k >= 0; --k)
            if (t - k >= 0) a += s0[t - k] * pk.k[k];
          lds[r * 51 + t] = a;
        }
      } else {
        const unsigned bits = __float_as_uint(lds[r * 51 + 50]);
        float sa[50];                         // full spike row
#pragma unroll
        for (int t = 0; t < 32; ++t) sa[t] = (bits >> t) & 1u ? 1.f : 0.f;
        // reconstruct refractory buffer state at t=32:
        // buf[(32+d)&15] = buf[d] = sum_{tau=16+d}^{31} s[tau]*rk.k[31+d-tau]
        // (ascending tau = reference accumulation order -> bit-exact)
        float buf[16];
#pragma unroll
        for (int d = 0; d < 16; ++d) {
          float a = 0.f;
#pragma unroll
          for (int tau = 16; tau <= 31; ++tau)
            if (tau >= 16 + d) a += sa[tau] * rk.k[31 + d - tau];
          buf[d] = a;
        }
        // spike t in [32,50) continuing the chain
#pragma unroll
        for (int t = 32; t < 50; ++t) {
          float v = u1[t - 32] + buf[t & 15];
          buf[t & 15] = 0.f;
          float sp = 0.f;
          if (v >= THETA) {
            sp = 1.f;
#pragma unroll
            for (int j = 0; j < 16; ++j) buf[(t + 1 + j) & 15] += rk.k[j];
          }
          sa[t] = sp;
        }
        // FIR2 unguarded, t in [32,50)
#pragma unroll
        for (int t = 32; t < 50; ++t) {
          float a = 0.f;
#pragma unroll
          for (int k = 31; k >= 0; --k)
            a += sa[t - k] * pk.k[k];
          lds[r * 51 + t] = a;
        }
      }
    }
  }
  __syncthreads();
  // ---- pool ((h0w0+h0w1)+h1w0)+h1w1 * 2.75 -> spike -> direct store ----
  if (tid < COUT * (SW / 2)) {                // 32 threads
    const int co = tid / (SW / 2);
    const int wpl = tid % (SW / 2);
    const int wop = group * (SW / 2) + wpl;   // s2 wo
    if (wop < S2W) {
      const int r00 = (co * 16 + 2 * wpl) * 51;
      const int r01 = (co * 16 + 2 * wpl + 1) * 51;
      const int r10 = (co * 16 + 8 + 2 * wpl) * 51;
      const int r11 = (co * 16 + 8 + 2 * wpl + 1) * 51;
      float* orow = s2out + (((size_t)(n * COUT + co) * S2H + hop) * S2W + wop) * 50;
      float buf[16];
#pragma unroll
      for (int j = 0; j < 16; ++j) buf[j] = 0.f;
      float prev = 0.f;
#pragma unroll
      for (int t = 0; t < 50; ++t) {
        const float u0 = (((lds[r00 + t] + lds[r01 + t]) + lds[r10 + t]) + lds[r11 + t]) * 2.75f;
        float v = u0 + buf[t & 15];
        buf[t & 15] = 0.f;
        float sp = 0.f;
        if (v >= THETA) {
          sp = 1.f;
#pragma unroll
          for (int j = 0; j < 16; ++j) buf[(t + 1 + j) & 15] += rk.k[j];
        }
        if (t & 1) *(float2*)(orow + t - 1) = make_float2(prev, sp);
        else prev = sp;
      }
    }
  }
}

// ====== L2 MERGED (R4-proven branchless conv, skip REVERTED): conv2 + psp3 +
//        spike3 + pool2 + psp4 + spike4 ======
template <int CIN, int COUT, int KK, int SW, int WT, int HIN, int WIN,
          int S1H, int S1W, int S2H, int S2W>
__global__ __launch_bounds__(256)
void conv_pps2_kernel(const float* __restrict__ x, const float* __restrict__ w,
                      float* __restrict__ s2out, K32 pk, K16 rk) {
  constexpr int XR = 2 * (WT - 1) + KK;       // 5
  constexpr int GROUPS = (S1W + SW - 1) / SW; // 8
  constexpr int NROW = COUT * 2 * SW;         // 128
  constexpr int NROWP = COUT * (SW / 2);      // 32 pooled rows
  __shared__ float lds[NROW * 51];            // 26 KB
  const int tid = threadIdx.x;
  const int wave = tid >> 6;
  const int lane = tid & 63;
  const int group = blockIdx.x % GROUPS;
  const int rest = blockIdx.x / GROUPS;
  const int hop = rest % S2H;                 // s2 ho
  const int n = rest / S2H;
  const int ho_off = wave & 1;
  const int wo_half = wave >> 1;
  const int ho = 2 * hop + ho_off;            // s1 ho
  const int wo0 = group * SW + wo_half * WT;
  const int tt = lane < 50 ? lane : 49;

  // ---- conv on raw s2 spikes (proven order c -> kh -> co -> kw -> wl) ----
  float acc[COUT][WT] = {};
  for (int c = 0; c < CIN; ++c) {
#pragma unroll
    for (int kh = 0; kh < KK; ++kh) {
      const int hi = 2 * ho + kh - 1;
      if ((unsigned)hi >= (unsigned)HIN) continue;   // zero padding
      float xr[XR];
#pragma unroll
      for (int i = 0; i < XR; ++i) {
        const int wi = 2 * wo0 - 1 + i;
        xr[i] = ((unsigned)wi < (unsigned)WIN)
                    ? x[(((size_t)(n * CIN + c) * HIN + hi) * WIN + wi) * 50 + tt]
                    : 0.f;
      }
#pragma unroll
      for (int co = 0; co < COUT; ++co)
#pragma unroll
        for (int kw = 0; kw < KK; ++kw) {
          const float wv = w[((co * CIN + c) * KK + kh) * KK + kw];
#pragma unroll
          for (int wl = 0; wl < WT; ++wl)
            acc[co][wl] += xr[2 * wl + kw] * wv;
        }
    }
  }
  // ---- transpose: LDS row = (co*2 + ho_off)*SW + wol ----
  if (lane < 50) {
#pragma unroll
    for (int co = 0; co < COUT; ++co)
#pragma unroll
      for (int wl = 0; wl < WT; ++wl)
        lds[((co * 2 + ho_off) * SW + wo_half * WT + wl) * 51 + lane] = acc[co][wl];
  }
  __syncthreads();
  // ---- FIR (psp3) on 128 conv rows: 2 thr/row, snapshot -> barrier -> in-place ----
  {
    const int r = tid & (NROW - 1);
    const int part = tid >> 7;                // 0: y[0..31], 1: y[32..49]
    float xs[50];
    if (part == 0) {
#pragma unroll
      for (int t = 0; t < 32; ++t) xs[t] = lds[r * 51 + t];
    } else {
#pragma unroll
      for (int t = 0; t < 50; ++t) xs[t] = lds[r * 51 + t];
    }
    __syncthreads();
    if (part == 0) {
#pragma unroll
      for (int t = 0; t < 32; ++t) {
        float a = 0.f;
#pragma unroll
        for (int k = 31; k >= 0; --k)
          if (t - k >= 0) a += xs[t - k] * pk.k[k];
        lds[r * 51 + t] = a;
      }
    } else {
#pragma unroll
      for (int t = 32; t < 50; ++t) {
        float a = 0.f;
#pragma unroll
        for (int k = 31; k >= 0; --k)
          a += xs[t - k] * pk.k[k];            // all taps valid for t >= 32
        lds[r * 51 + t] = a;
      }
    }
  }
  __syncthreads();
  // ---- spike3 per row (128 rows, in place) ----
  if (tid < NROW) {
    float buf[16];
#pragma unroll
    for (int j = 0; j < 16; ++j) buf[j] = 0.f;
#pragma unroll
    for (int t = 0; t < 50; ++t) {
      float v = lds[tid * 51 + t] + buf[t & 15];
      buf[t & 15] = 0.f;
      float sp = 0.f;
      if (v >= THETA) {
        sp = 1.f;
#pragma unroll
        for (int j = 0; j < 16; ++j) buf[(t + 1 + j) & 15] += rk.k[j];
      }
      lds[tid * 51 + t] = sp;
    }
  }
  __syncthreads();
  // ---- pool-sum + FIR (psp4) on 32 pooled rows: 2 thr/row ----
  {
    const int r = tid & (NROWP - 1);
    const int part = tid >> 5;                // 0..7, only part<2 active
    const bool act = part < 2;
    const int co = r / (SW / 2);
    const int wpl = r % (SW / 2);
    const int r00 = ((co * 2) * SW + 2 * wpl) * 51;
    const int r01 = r00 + 51;
    const int r10 = ((co * 2 + 1) * SW + 2 * wpl) * 51;
    const int r11 = r10 + 51;
    float xs[50];
    if (act) {
      if (part == 0) {
#pragma unroll
        for (int t = 0; t < 32; ++t)
          xs[t] = (((lds[r00 + t] + lds[r01 + t]) + lds[r10 + t]) + lds[r11 + t]) * 2.75f;
      } else {
#pragma unroll
        for (int t = 0; t < 50; ++t)
          xs[t] = (((lds[r00 + t] + lds[r01 + t]) + lds[r10 + t]) + lds[r11 + t]) * 2.75f;
      }
    }
    __syncthreads();
    if (act) {
      if (part == 0) {
#pragma unroll
        for (int t = 0; t < 32; ++t) {
          float a = 0.f;
#pragma unroll
          for (int k = 31; k >= 0; --k)
            if (t - k >= 0) a += xs[t - k] * pk.k[k];
          lds[r00 + t] = a;
        }
      } else {
#pragma unroll
        for (int t = 32; t < 50; ++t) {
          float a = 0.f;
#pragma unroll
          for (int k = 31; k >= 0; --k)
            a += xs[t - k] * pk.k[k];
          lds[r00 + t] = a;
        }
      }
    }
  }
  __syncthreads();
  // ---- spike4 -> direct store ----
  if (tid < NROWP) {
    const int co = tid / (SW / 2);
    const int wpl = tid % (SW / 2);
    const int wop = group * (SW / 2) + wpl;   // s2 wo
    if (wop < S2W) {
      const int r00 = ((co * 2) * SW + 2 * wpl) * 51;
      float* orow = s2out + (((size_t)(n * COUT + co) * S2H + hop) * S2W + wop) * 50;
      float buf[16];
#pragma unroll
      for (int j = 0; j < 16; ++j) buf[j] = 0.f;
      float prev = 0.f;
#pragma unroll
      for (int t = 0; t < 50; ++t) {
        float v = lds[r00 + t] + buf[t & 15];
        buf[t & 15] = 0.f;
        float sp = 0.f;
        if (v >= THETA) {
          sp = 1.f;
#pragma unroll
          for (int j = 0; j < 16; ++j) buf[(t + 1 + j) & 15] += rk.k[j];
        }
        if (t & 1) *(float2*)(orow + t - 1) = make_float2(prev, sp);
        else prev = sp;
      }
    }
  }
}

// ====== fused conv (stride2,pad1) + psp(commuted) + spike (verified, L3 only) ======
template <int CIN, int COUT, int KK, int WT, int HIN, int WIN, int HOUT, int WOUT>
__global__ __launch_bounds__(256)
void conv_fir_spike_kernel(const float* __restrict__ x, const float* __restrict__ w,
                           float* __restrict__ s, K32 pk, K16 rk) {
  constexpr int XR = 2 * (WT - 1) + KK;
  constexpr int TW = 4 * WT;                 // wo span per block (4 waves)
  constexpr int GROUPS = (WOUT + TW - 1) / TW;
  constexpr int NROW = COUT * TW;
  __shared__ float lds[NROW * 51];
  const int tid = threadIdx.x;
  const int wave = tid >> 6;
  const int lane = tid & 63;
  const int group = blockIdx.x % GROUPS;
  const int rest = blockIdx.x / GROUPS;
  const int ho = rest % HOUT;
  const int n = rest / HOUT;
  const int wo0 = group * TW + wave * WT;
  const int tt = lane < 50 ? lane : 49;

  float acc[COUT][WT] = {};
  for (int c = 0; c < CIN; ++c) {
#pragma unroll
    for (int kh = 0; kh < KK; ++kh) {
      const int hi = 2 * ho + kh - 1;
      if ((unsigned)hi >= (unsigned)HIN) continue;   // zero padding
      float xr[XR];
#pragma unroll
      for (int i = 0; i < XR; ++i) {
        const int wi = 2 * wo0 - 1 + i;
        xr[i] = ((unsigned)wi < (unsigned)WIN)
                    ? x[(((size_t)(n * CIN + c) * HIN + hi) * WIN + wi) * 50 + tt]
                    : 0.f;
      }
#pragma unroll
      for (int co = 0; co < COUT; ++co)
#pragma unroll
        for (int kw = 0; kw < KK; ++kw) {
          const float wv = w[((co * CIN + c) * KK + kh) * KK + kw];
#pragma unroll
          for (int wl = 0; wl < WT; ++wl)
            acc[co][wl] += xr[2 * wl + kw] * wv;
        }
    }
  }

  if (lane < 50) {
#pragma unroll
    for (int co = 0; co < COUT; ++co)
#pragma unroll
      for (int wl = 0; wl < WT; ++wl)
        lds[(co * TW + wave * WT + wl) * 51 + lane] = acc[co][wl];
  }
  __syncthreads();
  // ---- FIR = psp (commuted past conv): 2 threads/row ----
  {
    const int r = tid % NROW;
    const int part = tid / NROW;
    const int wol = r % TW;
    const bool act = (part < 2) && (group * TW + wol < WOUT);
    float xs[50];
    if (act) {
      if (part == 0) {
#pragma unroll
        for (int t = 0; t < 25; ++t) xs[t] = lds[r * 51 + t];
      } else {
#pragma unroll
        for (int t = 0; t < 50; ++t) xs[t] = lds[r * 51 + t];
      }
    }
    __syncthreads();
    if (act) {
      if (part == 0) {
#pragma unroll
        for (int t = 0; t < 25; ++t) {
          float a = 0.f;
#pragma unroll
          for (int k = 31; k >= 0; --k)
            if (t - k >= 0) a += xs[t - k] * pk.k[k];
          lds[r * 51 + t] = a;
        }
      } else {
#pragma unroll
        for (int t = 25; t < 50; ++t) {
          float a = 0.f;
#pragma unroll
          for (int k = 31; k >= 0; --k)
            if (t - k >= 0) a += xs[t - k] * pk.k[k];
          lds[r * 51 + t] = a;
        }
      }
    }
  }
  __syncthreads();
  // spike along t, one thread per output row, direct float2 store from regs
  if (tid < NROW) {
    const int co = tid / TW;
    const int wol = tid - co * TW;
    const int wo = group * TW + wol;
    if (wo < WOUT) {
      float* orow = s + (((size_t)(n * COUT + co) * HOUT + ho) * WOUT + wo) * 50;
      float buf[16];
#pragma unroll
      for (int j = 0; j < 16; ++j) buf[j] = 0.f;
      float prev = 0.f;
#pragma unroll
      for (int t = 0; t < 50; ++t) {
        float v = lds[tid * 51 + t] + buf[t & 15];
        buf[t & 15] = 0.f;
        float sp = 0.f;
        if (v >= THETA) {
          sp = 1.f;
#pragma unroll
          for (int j = 0; j < 16; ++j) buf[(t + 1 + j) & 15] += rk.k[j];
        }
        if (t & 1) *(float2*)(orow + t - 1) = make_float2(prev, sp);
        else prev = sp;
      }
    }
  }
}

// ====== fc + psp(commuted) + final spike (verified) ======
__global__ __launch_bounds__(512)
void fc_fir_spike_kernel(const float* __restrict__ w, const float* __restrict__ s,
                         float* __restrict__ out, K32 pk, K16 rk) {
  __shared__ float lds[8 * 51];
  const int tid = threadIdx.x;
  const int wave = tid >> 6, lane = tid & 63;
  const int o = wave & 1, n = wave >> 1;
  const int tt = lane < 50 ? lane : 49;
  const float* wrow = w + (size_t)o * 2048;
  const float* ub = s + (size_t)n * 2048 * 50;
  float acc = 0.f;
#pragma unroll 32
  for (int i = 0; i < 2048; ++i) acc += wrow[i] * ub[(size_t)i * 50 + tt];
  if (lane < 50) lds[wave * 51 + lane] = acc;
  __syncthreads();
  // ---- FIR = psp6 (commuted past einsum): 2 threads/row, in place ----
  {
    const int r = tid & 7;
    const int part = tid >> 3;      // only part<2 active
    const bool act = part < 2;
    float xs[50];
    if (act) {
      if (part == 0) {
#pragma unroll
        for (int t = 0; t < 25; ++t) xs[t] = lds[r * 51 + t];
      } else {
#pragma unroll
        for (int t = 0; t < 50; ++t) xs[t] = lds[r * 51 + t];
      }
    }
    __syncthreads();
    if (act) {
      if (part == 0) {
#pragma unroll
        for (int t = 0; t < 25; ++t) {
          float a = 0.f;
#pragma unroll
          for (int k = 31; k >= 0; --k)
            if (t - k >= 0) a += xs[t - k] * pk.k[k];
          lds[r * 51 + t] = a;
        }
      } else {
#pragma unroll
        for (int t = 25; t < 50; ++t) {
          float a = 0.f;
#pragma unroll
          for (int k = 31; k >= 0; --k)
            if (t - k >= 0) a += xs[t - k] * pk.k[k];
          lds[r * 51 + t] = a;
        }
      }
    }
  }
  __syncthreads();
  if (tid < 8) {
    float buf[16];
#pragma unroll
    for (int j = 0; j < 16; ++j) buf[j] = 0.f;
#pragma unroll
    for (int t = 0; t < 50; ++t) {
      float v = lds[tid * 51 + t] + buf[t & 15];
      buf[t & 15] = 0.f;
      float sp = 0.f;
      if (v >= THETA) {
        sp = 1.f;
#pragma unroll
        for (int j = 0; j < 16; ++j) buf[(t + 1 + j) & 15] += rk.k[j];
      }
      out[tid * 50 + t] = sp;
    }
  }
}

extern "C" void kernel_launch(void* const* d_in, const int* in_sizes, int n_in,
                              void* d_out, int out_size, void* d_ws, size_t ws_size,
                              hipStream_t stream) {
  const float* xin = (const float*)d_in[0];  // [4,2,256,256,50] raw binary spikes
  const float* w1  = (const float*)d_in[1];  // [8,2,5,5]
  const float* w2  = (const float*)d_in[2];  // [16,8,3,3]
  const float* w3  = (const float*)d_in[3];  // [32,16,3,3]
  const float* wfc = (const float*)d_in[4];  // [2,32,8,8]
  float* out = (float*)d_out;                // [4,2,1,1,50]

  float* R0 = (float*)d_ws;                  // 26,214,400 floats
  float* R1 = R0 + 26214400;

  K32 pk;
  for (int k = 0; k < 32; ++k)
    pk.k[k] = (float)(((double)k / 10.0) * exp(1.0 - (double)k / 10.0));
  K16 rk;
  for (int j = 0; j < 16; ++j) {
    const double tr = (double)(j + 1);
    rk.k[j] = (float)(-2.0 * 10.0 * tr * exp(1.0 - tr));
  }

  // 1. FULLY FUSED L1: conv1(raw x)+psp1+spike1+psp2+pool1+spike2: xin -> R1 = s2
  conv_pps_kernel<2, 8, 5, 256, 256, 127, 127, 63, 63>
      <<<4 * 63 * 16, 256, 0, stream>>>(xin, w1, R1, pk, rk);
  // 2. MERGED L2: conv2+psp3+spike3+pool2+psp4+spike4: R1 -> R0 = s4 [4,16,16,16,50]
  conv_pps2_kernel<8, 16, 3, 4, 2, 63, 63, 32, 32, 16, 16>
      <<<4 * 16 * 8, 256, 0, stream>>>(R1, w2, R0, pk, rk);
  // 3. FUSED conv3+psp5+spike5: R0 -> R1 = s5 [4,32,8,8,50]
  conv_fir_spike_kernel<16, 32, 3, 1, 16, 16, 8, 8>
      <<<4 * 8 * 2, 256, 0, stream>>>(R0, w3, R1, pk, rk);
  // 4. FUSED fc+psp6+final spike: R1 -> out
  fc_fir_spike_kernel<<<1, 512, 0, stream>>>(wfc, R1, out, pk, rk);
}

// Round 9
// 453.739 us; speedup vs baseline: 1.3002x; 1.2986x over previous
//
#include <hip/hip_runtime.h>
#include <cmath>

struct K32 { float k[32]; };
struct K16 { float k[16]; };

#define THETA 10.0f

// ====== L1 FULLY FUSED (R9): conv1(raw x) + psp1 + spike1 + psp2 + pool1 +
//        spike2 -> s2.
// R8: FIR phase split-pipelined at T=32 via spike-bit relay (proven).
// R9: pool+spike phase also split at T=32: 2 thr/row; part0 runs chain t<32
//     then publishes its literal refractory buf[16] (exact state, no math);
//     part1 precomputes its pool-sums during part0's chain, then continues.
template <int CIN, int COUT, int KK, int HIN, int WIN, int S1H, int S1W,
          int S2H, int S2W>
__global__ __launch_bounds__(256)
void conv_pps_kernel(const float* __restrict__ x, const float* __restrict__ w,
                     float* __restrict__ s2out, K32 pk, K16 rk) {
  constexpr int WT = 4;                       // s1-wo per wave
  constexpr int SW = 8;                       // s1-wo per block
  constexpr int XR = 2 * (WT - 1) + KK;       // 11
  constexpr int GROUPS = (S1W + SW - 1) / SW; // 16
  constexpr int NROW = COUT * 2 * SW;         // 128
  __shared__ float lds[NROW * 51];            // 26 KB (col 50 = spike-bit relay)
  __shared__ float pbuf[32][16];              // pool-phase refractory relay (2 KB)
  const int tid = threadIdx.x;
  const int wave = tid >> 6;
  const int lane = tid & 63;
  const int group = blockIdx.x % GROUPS;
  const int rest = blockIdx.x / GROUPS;
  const int hop = rest % S2H;                 // s2 ho
  const int n = rest / S2H;
  const int ho_off = wave & 1;
  const int wo_half = wave >> 1;
  const int ho = 2 * hop + ho_off;            // s1 ho
  const int wo0 = group * SW + wo_half * WT;
  const int tt = lane < 50 ? lane : 49;

  // ---- conv on RAW binary spikes (proven order c -> kh -> co -> kw -> wl) ----
  float acc[COUT][WT] = {};
  for (int c = 0; c < CIN; ++c) {
#pragma unroll
    for (int kh = 0; kh < KK; ++kh) {
      const int hi = 2 * ho + kh - 1;
      if ((unsigned)hi >= (unsigned)HIN) continue;   // zero padding
      float xr[XR];
#pragma unroll
      for (int i = 0; i < XR; ++i) {
        const int wi = 2 * wo0 - 1 + i;
        xr[i] = ((unsigned)wi < (unsigned)WIN)
                    ? x[(((size_t)(n * CIN + c) * HIN + hi) * WIN + wi) * 50 + tt]
                    : 0.f;
      }
#pragma unroll
      for (int co = 0; co < COUT; ++co)
#pragma unroll
        for (int kw = 0; kw < KK; ++kw) {
          const float wv = w[((co * CIN + c) * KK + kh) * KK + kw];
#pragma unroll
          for (int wl = 0; wl < WT; ++wl)
            acc[co][wl] += xr[2 * wl + kw] * wv;
        }
    }
  }
  // ---- transpose: LDS row = co*16 + ho_off*8 + wol ----
  if (lane < 50) {
#pragma unroll
    for (int co = 0; co < COUT; ++co)
#pragma unroll
      for (int wl = 0; wl < WT; ++wl)
        lds[((co * 2 + ho_off) * SW + wo_half * WT + wl) * 51 + lane] = acc[co][wl];
  }
  __syncthreads();
  // ---- FUSED FIR1(psp1)+spike1+FIR2(psp2), split-pipelined at T=32 (R8) ----
  {
    const int r = tid & (NROW - 1);
    const int part = tid >> 7;                // 0: t<32, 1: t>=32
    const int wol = r & (SW - 1);
    const bool act = (group * SW + wol) < S1W;
    float xs[50];                             // conv output u-candidates
    if (act) {
      if (part == 0) {
#pragma unroll
        for (int t = 0; t < 32; ++t) xs[t] = lds[r * 51 + t];
      } else {
#pragma unroll
        for (int t = 0; t < 50; ++t) xs[t] = lds[r * 51 + t];
      }
    }
    __syncthreads();                          // snapshot done before any write
    float s0[32];                             // part0: u then spike prefix
    float u1[18];                             // part1: FIR1 outputs t in [32,50)
    if (act) {
      if (part == 0) {
        // FIR1 guarded, t<32 (identical arithmetic to proven prefix)
#pragma unroll
        for (int t = 0; t < 32; ++t) {
          float a = 0.f;
#pragma unroll
          for (int k = 31; k >= 0; --k)
            if (t - k >= 0) a += xs[t - k] * pk.k[k];
          s0[t] = a;
        }
        // spike prefix in regs; pack bits
        float buf[16];
#pragma unroll
        for (int j = 0; j < 16; ++j) buf[j] = 0.f;
        unsigned bits = 0u;
#pragma unroll
        for (int t = 0; t < 32; ++t) {
          float v = s0[t] + buf[t & 15];
          buf[t & 15] = 0.f;
          float sp = 0.f;
          if (v >= THETA) {
            sp = 1.f;
            bits |= (1u << t);
#pragma unroll
            for (int j = 0; j < 16; ++j) buf[(t + 1 + j) & 15] += rk.k[j];
          }
          s0[t] = sp;
        }
        lds[r * 51 + 50] = __uint_as_float(bits);   // relay spike prefix
      } else {
        // FIR1 unguarded, t in [32,50) (all 32 taps valid)
#pragma unroll
        for (int t = 32; t < 50; ++t) {
          float a = 0.f;
#pragma unroll
          for (int k = 31; k >= 0; --k)
            a += xs[t - k] * pk.k[k];
          u1[t - 32] = a;
        }
      }
    }
    __syncthreads();                          // publish bits before part1 reads
    if (act) {
      if (part == 0) {
        // FIR2 guarded, t<32, from own spike prefix
#pragma unroll
        for (int t = 0; t < 32; ++t) {
          float a = 0.f;
#pragma unroll
          for (int k = 31; k >= 0; --k)
            if (t - k >= 0) a += s0[t - k] * pk.k[k];
          lds[r * 51 + t] = a;
        }
      } else {
        const unsigned bits = __float_as_uint(lds[r * 51 + 50]);
        float sa[50];                         // full spike row
#pragma unroll
        for (int t = 0; t < 32; ++t) sa[t] = (bits >> t) & 1u ? 1.f : 0.f;
        // reconstruct refractory buffer state at t=32 (proven bit-exact, R8)
        float buf[16];
#pragma unroll
        for (int d = 0; d < 16; ++d) {
          float a = 0.f;
#pragma unroll
          for (int tau = 16; tau <= 31; ++tau)
            if (tau >= 16 + d) a += sa[tau] * rk.k[31 + d - tau];
          buf[d] = a;
        }
        // spike t in [32,50) continuing the chain
#pragma unroll
        for (int t = 32; t < 50; ++t) {
          float v = u1[t - 32] + buf[t & 15];
          buf[t & 15] = 0.f;
          float sp = 0.f;
          if (v >= THETA) {
            sp = 1.f;
#pragma unroll
            for (int j = 0; j < 16; ++j) buf[(t + 1 + j) & 15] += rk.k[j];
          }
          sa[t] = sp;
        }
        // FIR2 unguarded, t in [32,50)
#pragma unroll
        for (int t = 32; t < 50; ++t) {
          float a = 0.f;
#pragma unroll
          for (int k = 31; k >= 0; --k)
            a += sa[t - k] * pk.k[k];
          lds[r * 51 + t] = a;
        }
      }
    }
  }
  __syncthreads();
  // ---- pool+spike, split at T=32 with literal buf-state relay (R9) ----
  {
    const int r = tid & 31;                   // pooled row = co*4 + wpl
    const int part = (tid >> 5) & 1;
    const bool pact = tid < 64;
    const int co = r >> 2;
    const int wpl = r & 3;
    const int wop = group * (SW / 2) + wpl;   // s2 wo
    const bool act = pact && (wop < S2W);
    const int r00 = (co * 16 + 2 * wpl) * 51;
    const int r01 = (co * 16 + 2 * wpl + 1) * 51;
    const int r10 = (co * 16 + 8 + 2 * wpl) * 51;
    const int r11 = (co * 16 + 8 + 2 * wpl + 1) * 51;
    float* orow = s2out + (((size_t)(n * COUT + co) * S2H + hop) * S2W + wop) * 50;
    float u1[18];
    if (act && part == 1) {
      // precompute pool sums for t in [32,50) -- overlaps part0's chain
#pragma unroll
      for (int t = 32; t < 50; ++t)
        u1[t - 32] = (((lds[r00 + t] + lds[r01 + t]) + lds[r10 + t]) + lds[r11 + t]) * 2.75f;
    }
    if (act && part == 0) {
      float buf[16];
#pragma unroll
      for (int j = 0; j < 16; ++j) buf[j] = 0.f;
      float prev = 0.f;
#pragma unroll
      for (int t = 0; t < 32; ++t) {
        const float u0 = (((lds[r00 + t] + lds[r01 + t]) + lds[r10 + t]) + lds[r11 + t]) * 2.75f;
        float v = u0 + buf[t & 15];
        buf[t & 15] = 0.f;
        float sp = 0.f;
        if (v >= THETA) {
          sp = 1.f;
#pragma unroll
          for (int j = 0; j < 16; ++j) buf[(t + 1 + j) & 15] += rk.k[j];
        }
        if (t & 1) *(float2*)(orow + t - 1) = make_float2(prev, sp);
        else prev = sp;
      }
#pragma unroll
      for (int j = 0; j < 16; ++j) pbuf[r][j] = buf[j];   // literal state relay
    }
    __syncthreads();                          // all 256 threads
    if (act && part == 1) {
      float buf[16];
#pragma unroll
      for (int j = 0; j < 16; ++j) buf[j] = pbuf[r][j];   // exact continuation
      float prev = 0.f;
#pragma unroll
      for (int t = 32; t < 50; ++t) {
        float v = u1[t - 32] + buf[t & 15];
        buf[t & 15] = 0.f;
        float sp = 0.f;
        if (v >= THETA) {
          sp = 1.f;
#pragma unroll
          for (int j = 0; j < 16; ++j) buf[(t + 1 + j) & 15] += rk.k[j];
        }
        if (t & 1) *(float2*)(orow + t - 1) = make_float2(prev, sp);
        else prev = sp;
      }
    }
  }
}

// ====== L2 MERGED (R4-proven branchless conv): conv2 + psp3 + spike3 +
//        pool2 + psp4 + spike4 ======
template <int CIN, int COUT, int KK, int SW, int WT, int HIN, int WIN,
          int S1H, int S1W, int S2H, int S2W>
__global__ __launch_bounds__(256)
void conv_pps2_kernel(const float* __restrict__ x, const float* __restrict__ w,
                      float* __restrict__ s2out, K32 pk, K16 rk) {
  constexpr int XR = 2 * (WT - 1) + KK;       // 5
  constexpr int GROUPS = (S1W + SW - 1) / SW; // 8
  constexpr int NROW = COUT * 2 * SW;         // 128
  constexpr int NROWP = COUT * (SW / 2);      // 32 pooled rows
  __shared__ float lds[NROW * 51];            // 26 KB
  const int tid = threadIdx.x;
  const int wave = tid >> 6;
  const int lane = tid & 63;
  const int group = blockIdx.x % GROUPS;
  const int rest = blockIdx.x / GROUPS;
  const int hop = rest % S2H;                 // s2 ho
  const int n = rest / S2H;
  const int ho_off = wave & 1;
  const int wo_half = wave >> 1;
  const int ho = 2 * hop + ho_off;            // s1 ho
  const int wo0 = group * SW + wo_half * WT;
  const int tt = lane < 50 ? lane : 49;

  // ---- conv on raw s2 spikes (proven order c -> kh -> co -> kw -> wl) ----
  float acc[COUT][WT] = {};
  for (int c = 0; c < CIN; ++c) {
#pragma unroll
    for (int kh = 0; kh < KK; ++kh) {
      const int hi = 2 * ho + kh - 1;
      if ((unsigned)hi >= (unsigned)HIN) continue;   // zero padding
      float xr[XR];
#pragma unroll
      for (int i = 0; i < XR; ++i) {
        const int wi = 2 * wo0 - 1 + i;
        xr[i] = ((unsigned)wi < (unsigned)WIN)
                    ? x[(((size_t)(n * CIN + c) * HIN + hi) * WIN + wi) * 50 + tt]
                    : 0.f;
      }
#pragma unroll
      for (int co = 0; co < COUT; ++co)
#pragma unroll
        for (int kw = 0; kw < KK; ++kw) {
          const float wv = w[((co * CIN + c) * KK + kh) * KK + kw];
#pragma unroll
          for (int wl = 0; wl < WT; ++wl)
            acc[co][wl] += xr[2 * wl + kw] * wv;
        }
    }
  }
  // ---- transpose: LDS row = (co*2 + ho_off)*SW + wol ----
  if (lane < 50) {
#pragma unroll
    for (int co = 0; co < COUT; ++co)
#pragma unroll
      for (int wl = 0; wl < WT; ++wl)
        lds[((co * 2 + ho_off) * SW + wo_half * WT + wl) * 51 + lane] = acc[co][wl];
  }
  __syncthreads();
  // ---- FIR (psp3) on 128 conv rows: 2 thr/row, snapshot -> barrier -> in-place ----
  {
    const int r = tid & (NROW - 1);
    const int part = tid >> 7;                // 0: y[0..31], 1: y[32..49]
    float xs[50];
    if (part == 0) {
#pragma unroll
      for (int t = 0; t < 32; ++t) xs[t] = lds[r * 51 + t];
    } else {
#pragma unroll
      for (int t = 0; t < 50; ++t) xs[t] = lds[r * 51 + t];
    }
    __syncthreads();
    if (part == 0) {
#pragma unroll
      for (int t = 0; t < 32; ++t) {
        float a = 0.f;
#pragma unroll
        for (int k = 31; k >= 0; --k)
          if (t - k >= 0) a += xs[t - k] * pk.k[k];
        lds[r * 51 + t] = a;
      }
    } else {
#pragma unroll
      for (int t = 32; t < 50; ++t) {
        float a = 0.f;
#pragma unroll
        for (int k = 31; k >= 0; --k)
          a += xs[t - k] * pk.k[k];            // all taps valid for t >= 32
        lds[r * 51 + t] = a;
      }
    }
  }
  __syncthreads();
  // ---- spike3 per row (128 rows, in place) ----
  if (tid < NROW) {
    float buf[16];
#pragma unroll
    for (int j = 0; j < 16; ++j) buf[j] = 0.f;
#pragma unroll
    for (int t = 0; t < 50; ++t) {
      float v = lds[tid * 51 + t] + buf[t & 15];
      buf[t & 15] = 0.f;
      float sp = 0.f;
      if (v >= THETA) {
        sp = 1.f;
#pragma unroll
        for (int j = 0; j < 16; ++j) buf[(t + 1 + j) & 15] += rk.k[j];
      }
      lds[tid * 51 + t] = sp;
    }
  }
  __syncthreads();
  // ---- pool-sum + FIR (psp4) on 32 pooled rows: 2 thr/row ----
  {
    const int r = tid & (NROWP - 1);
    const int part = tid >> 5;                // 0..7, only part<2 active
    const bool act = part < 2;
    const int co = r / (SW / 2);
    const int wpl = r % (SW / 2);
    const int r00 = ((co * 2) * SW + 2 * wpl) * 51;
    const int r01 = r00 + 51;
    const int r10 = ((co * 2 + 1) * SW + 2 * wpl) * 51;
    const int r11 = r10 + 51;
    float xs[50];
    if (act) {
      if (part == 0) {
#pragma unroll
        for (int t = 0; t < 32; ++t)
          xs[t] = (((lds[r00 + t] + lds[r01 + t]) + lds[r10 + t]) + lds[r11 + t]) * 2.75f;
      } else {
#pragma unroll
        for (int t = 0; t < 50; ++t)
          xs[t] = (((lds[r00 + t] + lds[r01 + t]) + lds[r10 + t]) + lds[r11 + t]) * 2.75f;
      }
    }
    __syncthreads();
    if (act) {
      if (part == 0) {
#pragma unroll
        for (int t = 0; t < 32; ++t) {
          float a = 0.f;
#pragma unroll
          for (int k = 31; k >= 0; --k)
            if (t - k >= 0) a += xs[t - k] * pk.k[k];
          lds[r00 + t] = a;
        }
      } else {
#pragma unroll
        for (int t = 32; t < 50; ++t) {
          float a = 0.f;
#pragma unroll
          for (int k = 31; k >= 0; --k)
            a += xs[t - k] * pk.k[k];
          lds[r00 + t] = a;
        }
      }
    }
  }
  __syncthreads();
  // ---- spike4 -> direct store ----
  if (tid < NROWP) {
    const int co = tid / (SW / 2);
    const int wpl = tid % (SW / 2);
    const int wop = group * (SW / 2) + wpl;   // s2 wo
    if (wop < S2W) {
      const int r00 = ((co * 2) * SW + 2 * wpl) * 51;
      float* orow = s2out + (((size_t)(n * COUT + co) * S2H + hop) * S2W + wop) * 50;
      float buf[16];
#pragma unroll
      for (int j = 0; j < 16; ++j) buf[j] = 0.f;
      float prev = 0.f;
#pragma unroll
      for (int t = 0; t < 50; ++t) {
        float v = lds[r00 + t] + buf[t & 15];
        buf[t & 15] = 0.f;
        float sp = 0.f;
        if (v >= THETA) {
          sp = 1.f;
#pragma unroll
          for (int j = 0; j < 16; ++j) buf[(t + 1 + j) & 15] += rk.k[j];
        }
        if (t & 1) *(float2*)(orow + t - 1) = make_float2(prev, sp);
        else prev = sp;
      }
    }
  }
}

// ====== fused conv (stride2,pad1) + psp(commuted) + spike (verified, L3 only) ======
template <int CIN, int COUT, int KK, int WT, int HIN, int WIN, int HOUT, int WOUT>
__global__ __launch_bounds__(256)
void conv_fir_spike_kernel(const float* __restrict__ x, const float* __restrict__ w,
                           float* __restrict__ s, K32 pk, K16 rk) {
  constexpr int XR = 2 * (WT - 1) + KK;
  constexpr int TW = 4 * WT;                 // wo span per block (4 waves)
  constexpr int GROUPS = (WOUT + TW - 1) / TW;
  constexpr int NROW = COUT * TW;
  __shared__ float lds[NROW * 51];
  const int tid = threadIdx.x;
  const int wave = tid >> 6;
  const int lane = tid & 63;
  const int group = blockIdx.x % GROUPS;
  const int rest = blockIdx.x / GROUPS;
  const int ho = rest % HOUT;
  const int n = rest / HOUT;
  const int wo0 = group * TW + wave * WT;
  const int tt = lane < 50 ? lane : 49;

  float acc[COUT][WT] = {};
  for (int c = 0; c < CIN; ++c) {
#pragma unroll
    for (int kh = 0; kh < KK; ++kh) {
      const int hi = 2 * ho + kh - 1;
      if ((unsigned)hi >= (unsigned)HIN) continue;   // zero padding
      float xr[XR];
#pragma unroll
      for (int i = 0; i < XR; ++i) {
        const int wi = 2 * wo0 - 1 + i;
        xr[i] = ((unsigned)wi < (unsigned)WIN)
                    ? x[(((size_t)(n * CIN + c) * HIN + hi) * WIN + wi) * 50 + tt]
                    : 0.f;
      }
#pragma unroll
      for (int co = 0; co < COUT; ++co)
#pragma unroll
        for (int kw = 0; kw < KK; ++kw) {
          const float wv = w[((co * CIN + c) * KK + kh) * KK + kw];
#pragma unroll
          for (int wl = 0; wl < WT; ++wl)
            acc[co][wl] += xr[2 * wl + kw] * wv;
        }
    }
  }

  if (lane < 50) {
#pragma unroll
    for (int co = 0; co < COUT; ++co)
#pragma unroll
      for (int wl = 0; wl < WT; ++wl)
        lds[(co * TW + wave * WT + wl) * 51 + lane] = acc[co][wl];
  }
  __syncthreads();
  // ---- FIR = psp (commuted past conv): 2 threads/row ----
  {
    const int r = tid % NROW;
    const int part = tid / NROW;
    const int wol = r % TW;
    const bool act = (part < 2) && (group * TW + wol < WOUT);
    float xs[50];
    if (act) {
      if (part == 0) {
#pragma unroll
        for (int t = 0; t < 25; ++t) xs[t] = lds[r * 51 + t];
      } else {
#pragma unroll
        for (int t = 0; t < 50; ++t) xs[t] = lds[r * 51 + t];
      }
    }
    __syncthreads();
    if (act) {
      if (part == 0) {
#pragma unroll
        for (int t = 0; t < 25; ++t) {
          float a = 0.f;
#pragma unroll
          for (int k = 31; k >= 0; --k)
            if (t - k >= 0) a += xs[t - k] * pk.k[k];
          lds[r * 51 + t] = a;
        }
      } else {
#pragma unroll
        for (int t = 25; t < 50; ++t) {
          float a = 0.f;
#pragma unroll
          for (int k = 31; k >= 0; --k)
            if (t - k >= 0) a += xs[t - k] * pk.k[k];
          lds[r * 51 + t] = a;
        }
      }
    }
  }
  __syncthreads();
  // spike along t, one thread per output row, direct float2 store from regs
  if (tid < NROW) {
    const int co = tid / TW;
    const int wol = tid - co * TW;
    const int wo = group * TW + wol;
    if (wo < WOUT) {
      float* orow = s + (((size_t)(n * COUT + co) * HOUT + ho) * WOUT + wo) * 50;
      float buf[16];
#pragma unroll
      for (int j = 0; j < 16; ++j) buf[j] = 0.f;
      float prev = 0.f;
#pragma unroll
      for (int t = 0; t < 50; ++t) {
        float v = lds[tid * 51 + t] + buf[t & 15];
        buf[t & 15] = 0.f;
        float sp = 0.f;
        if (v >= THETA) {
          sp = 1.f;
#pragma unroll
          for (int j = 0; j < 16; ++j) buf[(t + 1 + j) & 15] += rk.k[j];
        }
        if (t & 1) *(float2*)(orow + t - 1) = make_float2(prev, sp);
        else prev = sp;
      }
    }
  }
}

// ====== fc + psp(commuted) + final spike (verified) ======
__global__ __launch_bounds__(512)
void fc_fir_spike_kernel(const float* __restrict__ w, const float* __restrict__ s,
                         float* __restrict__ out, K32 pk, K16 rk) {
  __shared__ float lds[8 * 51];
  const int tid = threadIdx.x;
  const int wave = tid >> 6, lane = tid & 63;
  const int o = wave & 1, n = wave >> 1;
  const int tt = lane < 50 ? lane : 49;
  const float* wrow = w + (size_t)o * 2048;
  const float* ub = s + (size_t)n * 2048 * 50;
  float acc = 0.f;
#pragma unroll 32
  for (int i = 0; i < 2048; ++i) acc += wrow[i] * ub[(size_t)i * 50 + tt];
  if (lane < 50) lds[wave * 51 + lane] = acc;
  __syncthreads();
  // ---- FIR = psp6 (commuted past einsum): 2 threads/row, in place ----
  {
    const int r = tid & 7;
    const int part = tid >> 3;      // only part<2 active
    const bool act = part < 2;
    float xs[50];
    if (act) {
      if (part == 0) {
#pragma unroll
        for (int t = 0; t < 25; ++t) xs[t] = lds[r * 51 + t];
      } else {
#pragma unroll
        for (int t = 0; t < 50; ++t) xs[t] = lds[r * 51 + t];
      }
    }
    __syncthreads();
    if (act) {
      if (part == 0) {
#pragma unroll
        for (int t = 0; t < 25; ++t) {
          float a = 0.f;
#pragma unroll
          for (int k = 31; k >= 0; --k)
            if (t - k >= 0) a += xs[t - k] * pk.k[k];
          lds[r * 51 + t] = a;
        }
      } else {
#pragma unroll
        for (int t = 25; t < 50; ++t) {
          float a = 0.f;
#pragma unroll
          for (int k = 31; k >= 0; --k)
            if (t - k >= 0) a += xs[t - k] * pk.k[k];
          lds[r * 51 + t] = a;
        }
      }
    }
  }
  __syncthreads();
  if (tid < 8) {
    float buf[16];
#pragma unroll
    for (int j = 0; j < 16; ++j) buf[j] = 0.f;
#pragma unroll
    for (int t = 0; t < 50; ++t) {
      float v = lds[tid * 51 + t] + buf[t & 15];
      buf[t & 15] = 0.f;
      float sp = 0.f;
      if (v >= THETA) {
        sp = 1.f;
#pragma unroll
        for (int j = 0; j < 16; ++j) buf[(t + 1 + j) & 15] += rk.k[j];
      }
      out[tid * 50 + t] = sp;
    }
  }
}

extern "C" void kernel_launch(void* const* d_in, const int* in_sizes, int n_in,
                              void* d_out, int out_size, void* d_ws, size_t ws_size,
                              hipStream_t stream) {
  const float* xin = (const float*)d_in[0];  // [4,2,256,256,50] raw binary spikes
  const float* w1  = (const float*)d_in[1];  // [8,2,5,5]
  const float* w2  = (const float*)d_in[2];  // [16,8,3,3]
  const float* w3  = (const float*)d_in[3];  // [32,16,3,3]
  const float* wfc = (const float*)d_in[4];  // [2,32,8,8]
  float* out = (float*)d_out;                // [4,2,1,1,50]

  float* R0 = (float*)d_ws;                  // 26,214,400 floats
  float* R1 = R0 + 26214400;

  K32 pk;
  for (int k = 0; k < 32; ++k)
    pk.k[k] = (float)(((double)k / 10.0) * exp(1.0 - (double)k / 10.0));
  K16 rk;
  for (int j = 0; j < 16; ++j) {
    const double tr = (double)(j + 1);
    rk.k[j] = (float)(-2.0 * 10.0 * tr * exp(1.0 - tr));
  }

  // 1. FULLY FUSED L1: conv1(raw x)+psp1+spike1+psp2+pool1+spike2: xin -> R1 = s2
  conv_pps_kernel<2, 8, 5, 256, 256, 127, 127, 63, 63>
      <<<4 * 63 * 16, 256, 0, stream>>>(xin, w1, R1, pk, rk);
  // 2. MERGED L2: conv2+psp3+spike3+pool2+psp4+spike4: R1 -> R0 = s4 [4,16,16,16,50]
  conv_pps2_kernel<8, 16, 3, 4, 2, 63, 63, 32, 32, 16, 16>
      <<<4 * 16 * 8, 256, 0, stream>>>(R1, w2, R0, pk, rk);
  // 3. FUSED conv3+psp5+spike5: R0 -> R1 = s5 [4,32,8,8,50]
  conv_fir_spike_kernel<16, 32, 3, 1, 16, 16, 8, 8>
      <<<4 * 8 * 2, 256, 0, stream>>>(R0, w3, R1, pk, rk);
  // 4. FUSED fc+psp6+final spike: R1 -> out
  fc_fir_spike_kernel<<<1, 512, 0, stream>>>(wfc, R1, out, pk, rk);
}

// Round 10
// 453.254 us; speedup vs baseline: 1.3016x; 1.0011x over previous
//
#include <hip/hip_runtime.h>
#include <cmath>

struct K32 { float k[32]; };
struct K16 { float k[16]; };

#define THETA 10.0f

// ====== L1 FULLY FUSED (R10): conv1(raw x) + psp1 + spike1 + psp2 + pool1 +
//        spike2 -> s2.
// R8: FIR phase split-pipelined at T=32 via spike-bit relay (proven).
// R10: pool+spike split at T=32 with refractory state relayed via __shfl
//      (part0/part1 are lanes 0-31/32-63 of wave 0 -> wave-synchronous);
//      deletes the pbuf LDS (+2KB) and the pool mid-barrier. LDS back to
//      26112 B -> 6 blocks/CU static occupancy (was 5).
template <int CIN, int COUT, int KK, int HIN, int WIN, int S1H, int S1W,
          int S2H, int S2W>
__global__ __launch_bounds__(256)
void conv_pps_kernel(const float* __restrict__ x, const float* __restrict__ w,
                     float* __restrict__ s2out, K32 pk, K16 rk) {
  constexpr int WT = 4;                       // s1-wo per wave
  constexpr int SW = 8;                       // s1-wo per block
  constexpr int XR = 2 * (WT - 1) + KK;       // 11
  constexpr int GROUPS = (S1W + SW - 1) / SW; // 16
  constexpr int NROW = COUT * 2 * SW;         // 128
  __shared__ float lds[NROW * 51];            // 26 KB (col 50 = spike-bit relay)
  const int tid = threadIdx.x;
  const int wave = tid >> 6;
  const int lane = tid & 63;
  const int group = blockIdx.x % GROUPS;
  const int rest = blockIdx.x / GROUPS;
  const int hop = rest % S2H;                 // s2 ho
  const int n = rest / S2H;
  const int ho_off = wave & 1;
  const int wo_half = wave >> 1;
  const int ho = 2 * hop + ho_off;            // s1 ho
  const int wo0 = group * SW + wo_half * WT;
  const int tt = lane < 50 ? lane : 49;

  // ---- conv on RAW binary spikes (proven order c -> kh -> co -> kw -> wl) ----
  float acc[COUT][WT] = {};
  for (int c = 0; c < CIN; ++c) {
#pragma unroll
    for (int kh = 0; kh < KK; ++kh) {
      const int hi = 2 * ho + kh - 1;
      if ((unsigned)hi >= (unsigned)HIN) continue;   // zero padding
      float xr[XR];
#pragma unroll
      for (int i = 0; i < XR; ++i) {
        const int wi = 2 * wo0 - 1 + i;
        xr[i] = ((unsigned)wi < (unsigned)WIN)
                    ? x[(((size_t)(n * CIN + c) * HIN + hi) * WIN + wi) * 50 + tt]
                    : 0.f;
      }
#pragma unroll
      for (int co = 0; co < COUT; ++co)
#pragma unroll
        for (int kw = 0; kw < KK; ++kw) {
          const float wv = w[((co * CIN + c) * KK + kh) * KK + kw];
#pragma unroll
          for (int wl = 0; wl < WT; ++wl)
            acc[co][wl] += xr[2 * wl + kw] * wv;
        }
    }
  }
  // ---- transpose: LDS row = co*16 + ho_off*8 + wol ----
  if (lane < 50) {
#pragma unroll
    for (int co = 0; co < COUT; ++co)
#pragma unroll
      for (int wl = 0; wl < WT; ++wl)
        lds[((co * 2 + ho_off) * SW + wo_half * WT + wl) * 51 + lane] = acc[co][wl];
  }
  __syncthreads();
  // ---- FUSED FIR1(psp1)+spike1+FIR2(psp2), split-pipelined at T=32 (R8) ----
  {
    const int r = tid & (NROW - 1);
    const int part = tid >> 7;                // 0: t<32, 1: t>=32
    const int wol = r & (SW - 1);
    const bool act = (group * SW + wol) < S1W;
    float xs[50];                             // conv output u-candidates
    if (act) {
      if (part == 0) {
#pragma unroll
        for (int t = 0; t < 32; ++t) xs[t] = lds[r * 51 + t];
      } else {
#pragma unroll
        for (int t = 0; t < 50; ++t) xs[t] = lds[r * 51 + t];
      }
    }
    __syncthreads();                          // snapshot done before any write
    float s0[32];                             // part0: u then spike prefix
    float u1[18];                             // part1: FIR1 outputs t in [32,50)
    if (act) {
      if (part == 0) {
        // FIR1 guarded, t<32 (identical arithmetic to proven prefix)
#pragma unroll
        for (int t = 0; t < 32; ++t) {
          float a = 0.f;
#pragma unroll
          for (int k = 31; k >= 0; --k)
            if (t - k >= 0) a += xs[t - k] * pk.k[k];
          s0[t] = a;
        }
        // spike prefix in regs; pack bits
        float buf[16];
#pragma unroll
        for (int j = 0; j < 16; ++j) buf[j] = 0.f;
        unsigned bits = 0u;
#pragma unroll
        for (int t = 0; t < 32; ++t) {
          float v = s0[t] + buf[t & 15];
          buf[t & 15] = 0.f;
          float sp = 0.f;
          if (v >= THETA) {
            sp = 1.f;
            bits |= (1u << t);
#pragma unroll
            for (int j = 0; j < 16; ++j) buf[(t + 1 + j) & 15] += rk.k[j];
          }
          s0[t] = sp;
        }
        lds[r * 51 + 50] = __uint_as_float(bits);   // relay spike prefix
      } else {
        // FIR1 unguarded, t in [32,50) (all 32 taps valid)
#pragma unroll
        for (int t = 32; t < 50; ++t) {
          float a = 0.f;
#pragma unroll
          for (int k = 31; k >= 0; --k)
            a += xs[t - k] * pk.k[k];
          u1[t - 32] = a;
        }
      }
    }
    __syncthreads();                          // publish bits before part1 reads
    if (act) {
      if (part == 0) {
        // FIR2 guarded, t<32, from own spike prefix
#pragma unroll
        for (int t = 0; t < 32; ++t) {
          float a = 0.f;
#pragma unroll
          for (int k = 31; k >= 0; --k)
            if (t - k >= 0) a += s0[t - k] * pk.k[k];
          lds[r * 51 + t] = a;
        }
      } else {
        const unsigned bits = __float_as_uint(lds[r * 51 + 50]);
        float sa[50];                         // full spike row
#pragma unroll
        for (int t = 0; t < 32; ++t) sa[t] = (bits >> t) & 1u ? 1.f : 0.f;
        // reconstruct refractory buffer state at t=32 (proven bit-exact, R8)
        float buf[16];
#pragma unroll
        for (int d = 0; d < 16; ++d) {
          float a = 0.f;
#pragma unroll
          for (int tau = 16; tau <= 31; ++tau)
            if (tau >= 16 + d) a += sa[tau] * rk.k[31 + d - tau];
          buf[d] = a;
        }
        // spike t in [32,50) continuing the chain
#pragma unroll
        for (int t = 32; t < 50; ++t) {
          float v = u1[t - 32] + buf[t & 15];
          buf[t & 15] = 0.f;
          float sp = 0.f;
          if (v >= THETA) {
            sp = 1.f;
#pragma unroll
            for (int j = 0; j < 16; ++j) buf[(t + 1 + j) & 15] += rk.k[j];
          }
          sa[t] = sp;
        }
        // FIR2 unguarded, t in [32,50)
#pragma unroll
        for (int t = 32; t < 50; ++t) {
          float a = 0.f;
#pragma unroll
          for (int k = 31; k >= 0; --k)
            a += sa[t - k] * pk.k[k];
          lds[r * 51 + t] = a;
        }
      }
    }
  }
  __syncthreads();
  // ---- pool+spike, split at T=32, refractory state relayed via shfl (R10) ----
  {
    const int r = tid & 31;                   // pooled row = co*4 + wpl
    const int part = (tid >> 5) & 1;          // lanes 0-31 / 32-63 of wave 0
    const bool pact = tid < 64;
    const int co = r >> 2;
    const int wpl = r & 3;
    const int wop = group * (SW / 2) + wpl;   // s2 wo
    const bool act = pact && (wop < S2W);
    const int r00 = (co * 16 + 2 * wpl) * 51;
    const int r01 = (co * 16 + 2 * wpl + 1) * 51;
    const int r10 = (co * 16 + 8 + 2 * wpl) * 51;
    const int r11 = (co * 16 + 8 + 2 * wpl + 1) * 51;
    float* orow = s2out + (((size_t)(n * COUT + co) * S2H + hop) * S2W + wop) * 50;
    float u1[18];
    if (act && part == 1) {
      // pool sums for t in [32,50)
#pragma unroll
      for (int t = 32; t < 50; ++t)
        u1[t - 32] = (((lds[r00 + t] + lds[r01 + t]) + lds[r10 + t]) + lds[r11 + t]) * 2.75f;
    }
    float buf[16];
#pragma unroll
    for (int j = 0; j < 16; ++j) buf[j] = 0.f;
    if (act && part == 0) {
      float prev = 0.f;
#pragma unroll
      for (int t = 0; t < 32; ++t) {
        const float u0 = (((lds[r00 + t] + lds[r01 + t]) + lds[r10 + t]) + lds[r11 + t]) * 2.75f;
        float v = u0 + buf[t & 15];
        buf[t & 15] = 0.f;
        float sp = 0.f;
        if (v >= THETA) {
          sp = 1.f;
#pragma unroll
          for (int j = 0; j < 16; ++j) buf[(t + 1 + j) & 15] += rk.k[j];
        }
        if (t & 1) *(float2*)(orow + t - 1) = make_float2(prev, sp);
        else prev = sp;
      }
    }
    if (pact) {
      // wave-synchronous literal state relay: lane l reads lane l&31
#pragma unroll
      for (int j = 0; j < 16; ++j) buf[j] = __shfl(buf[j], tid & 31, 64);
    }
    if (act && part == 1) {
      float prev = 0.f;
#pragma unroll
      for (int t = 32; t < 50; ++t) {
        float v = u1[t - 32] + buf[t & 15];
        buf[t & 15] = 0.f;
        float sp = 0.f;
        if (v >= THETA) {
          sp = 1.f;
#pragma unroll
          for (int j = 0; j < 16; ++j) buf[(t + 1 + j) & 15] += rk.k[j];
        }
        if (t & 1) *(float2*)(orow + t - 1) = make_float2(prev, sp);
        else prev = sp;
      }
    }
  }
}

// ====== L2 MERGED (R4-proven branchless conv): conv2 + psp3 + spike3 +
//        pool2 + psp4 + spike4 ======
template <int CIN, int COUT, int KK, int SW, int WT, int HIN, int WIN,
          int S1H, int S1W, int S2H, int S2W>
__global__ __launch_bounds__(256)
void conv_pps2_kernel(const float* __restrict__ x, const float* __restrict__ w,
                      float* __restrict__ s2out, K32 pk, K16 rk) {
  constexpr int XR = 2 * (WT - 1) + KK;       // 5
  constexpr int GROUPS = (S1W + SW - 1) / SW; // 8
  constexpr int NROW = COUT * 2 * SW;         // 128
  constexpr int NROWP = COUT * (SW / 2);      // 32 pooled rows
  __shared__ float lds[NROW * 51];            // 26 KB
  const int tid = threadIdx.x;
  const int wave = tid >> 6;
  const int lane = tid & 63;
  const int group = blockIdx.x % GROUPS;
  const int rest = blockIdx.x / GROUPS;
  const int hop = rest % S2H;                 // s2 ho
  const int n = rest / S2H;
  const int ho_off = wave & 1;
  const int wo_half = wave >> 1;
  const int ho = 2 * hop + ho_off;            // s1 ho
  const int wo0 = group * SW + wo_half * WT;
  const int tt = lane < 50 ? lane : 49;

  // ---- conv on raw s2 spikes (proven order c -> kh -> co -> kw -> wl) ----
  float acc[COUT][WT] = {};
  for (int c = 0; c < CIN; ++c) {
#pragma unroll
    for (int kh = 0; kh < KK; ++kh) {
      const int hi = 2 * ho + kh - 1;
      if ((unsigned)hi >= (unsigned)HIN) continue;   // zero padding
      float xr[XR];
#pragma unroll
      for (int i = 0; i < XR; ++i) {
        const int wi = 2 * wo0 - 1 + i;
        xr[i] = ((unsigned)wi < (unsigned)WIN)
                    ? x[(((size_t)(n * CIN + c) * HIN + hi) * WIN + wi) * 50 + tt]
                    : 0.f;
      }
#pragma unroll
      for (int co = 0; co < COUT; ++co)
#pragma unroll
        for (int kw = 0; kw < KK; ++kw) {
          const float wv = w[((co * CIN + c) * KK + kh) * KK + kw];
#pragma unroll
          for (int wl = 0; wl < WT; ++wl)
            acc[co][wl] += xr[2 * wl + kw] * wv;
        }
    }
  }
  // ---- transpose: LDS row = (co*2 + ho_off)*SW + wol ----
  if (lane < 50) {
#pragma unroll
    for (int co = 0; co < COUT; ++co)
#pragma unroll
      for (int wl = 0; wl < WT; ++wl)
        lds[((co * 2 + ho_off) * SW + wo_half * WT + wl) * 51 + lane] = acc[co][wl];
  }
  __syncthreads();
  // ---- FIR (psp3) on 128 conv rows: 2 thr/row, snapshot -> barrier -> in-place ----
  {
    const int r = tid & (NROW - 1);
    const int part = tid >> 7;                // 0: y[0..31], 1: y[32..49]
    float xs[50];
    if (part == 0) {
#pragma unroll
      for (int t = 0; t < 32; ++t) xs[t] = lds[r * 51 + t];
    } else {
#pragma unroll
      for (int t = 0; t < 50; ++t) xs[t] = lds[r * 51 + t];
    }
    __syncthreads();
    if (part == 0) {
#pragma unroll
      for (int t = 0; t < 32; ++t) {
        float a = 0.f;
#pragma unroll
        for (int k = 31; k >= 0; --k)
          if (t - k >= 0) a += xs[t - k] * pk.k[k];
        lds[r * 51 + t] = a;
      }
    } else {
#pragma unroll
      for (int t = 32; t < 50; ++t) {
        float a = 0.f;
#pragma unroll
        for (int k = 31; k >= 0; --k)
          a += xs[t - k] * pk.k[k];            // all taps valid for t >= 32
        lds[r * 51 + t] = a;
      }
    }
  }
  __syncthreads();
  // ---- spike3 per row (128 rows, in place) ----
  if (tid < NROW) {
    float buf[16];
#pragma unroll
    for (int j = 0; j < 16; ++j) buf[j] = 0.f;
#pragma unroll
    for (int t = 0; t < 50; ++t) {
      float v = lds[tid * 51 + t] + buf[t & 15];
      buf[t & 15] = 0.f;
      float sp = 0.f;
      if (v >= THETA) {
        sp = 1.f;
#pragma unroll
        for (int j = 0; j < 16; ++j) buf[(t + 1 + j) & 15] += rk.k[j];
      }
      lds[tid * 51 + t] = sp;
    }
  }
  __syncthreads();
  // ---- pool-sum + FIR (psp4) on 32 pooled rows: 2 thr/row ----
  {
    const int r = tid & (NROWP - 1);
    const int part = tid >> 5;                // 0..7, only part<2 active
    const bool act = part < 2;
    const int co = r / (SW / 2);
    const int wpl = r % (SW / 2);
    const int r00 = ((co * 2) * SW + 2 * wpl) * 51;
    const int r01 = r00 + 51;
    const int r10 = ((co * 2 + 1) * SW + 2 * wpl) * 51;
    const int r11 = r10 + 51;
    float xs[50];
    if (act) {
      if (part == 0) {
#pragma unroll
        for (int t = 0; t < 32; ++t)
          xs[t] = (((lds[r00 + t] + lds[r01 + t]) + lds[r10 + t]) + lds[r11 + t]) * 2.75f;
      } else {
#pragma unroll
        for (int t = 0; t < 50; ++t)
          xs[t] = (((lds[r00 + t] + lds[r01 + t]) + lds[r10 + t]) + lds[r11 + t]) * 2.75f;
      }
    }
    __syncthreads();
    if (act) {
      if (part == 0) {
#pragma unroll
        for (int t = 0; t < 32; ++t) {
          float a = 0.f;
#pragma unroll
          for (int k = 31; k >= 0; --k)
            if (t - k >= 0) a += xs[t - k] * pk.k[k];
          lds[r00 + t] = a;
        }
      } else {
#pragma unroll
        for (int t = 32; t < 50; ++t) {
          float a = 0.f;
#pragma unroll
          for (int k = 31; k >= 0; --k)
            a += xs[t - k] * pk.k[k];
          lds[r00 + t] = a;
        }
      }
    }
  }
  __syncthreads();
  // ---- spike4 -> direct store ----
  if (tid < NROWP) {
    const int co = tid / (SW / 2);
    const int wpl = tid % (SW / 2);
    const int wop = group * (SW / 2) + wpl;   // s2 wo
    if (wop < S2W) {
      const int r00 = ((co * 2) * SW + 2 * wpl) * 51;
      float* orow = s2out + (((size_t)(n * COUT + co) * S2H + hop) * S2W + wop) * 50;
      float buf[16];
#pragma unroll
      for (int j = 0; j < 16; ++j) buf[j] = 0.f;
      float prev = 0.f;
#pragma unroll
      for (int t = 0; t < 50; ++t) {
        float v = lds[r00 + t] + buf[t & 15];
        buf[t & 15] = 0.f;
        float sp = 0.f;
        if (v >= THETA) {
          sp = 1.f;
#pragma unroll
          for (int j = 0; j < 16; ++j) buf[(t + 1 + j) & 15] += rk.k[j];
        }
        if (t & 1) *(float2*)(orow + t - 1) = make_float2(prev, sp);
        else prev = sp;
      }
    }
  }
}

// ====== fused conv (stride2,pad1) + psp(commuted) + spike (verified, L3 only) ======
template <int CIN, int COUT, int KK, int WT, int HIN, int WIN, int HOUT, int WOUT>
__global__ __launch_bounds__(256)
void conv_fir_spike_kernel(const float* __restrict__ x, const float* __restrict__ w,
                           float* __restrict__ s, K32 pk, K16 rk) {
  constexpr int XR = 2 * (WT - 1) + KK;
  constexpr int TW = 4 * WT;                 // wo span per block (4 waves)
  constexpr int GROUPS = (WOUT + TW - 1) / TW;
  constexpr int NROW = COUT * TW;
  __shared__ float lds[NROW * 51];
  const int tid = threadIdx.x;
  const int wave = tid >> 6;
  const int lane = tid & 63;
  const int group = blockIdx.x % GROUPS;
  const int rest = blockIdx.x / GROUPS;
  const int ho = rest % HOUT;
  const int n = rest / HOUT;
  const int wo0 = group * TW + wave * WT;
  const int tt = lane < 50 ? lane : 49;

  float acc[COUT][WT] = {};
  for (int c = 0; c < CIN; ++c) {
#pragma unroll
    for (int kh = 0; kh < KK; ++kh) {
      const int hi = 2 * ho + kh - 1;
      if ((unsigned)hi >= (unsigned)HIN) continue;   // zero padding
      float xr[XR];
#pragma unroll
      for (int i = 0; i < XR; ++i) {
        const int wi = 2 * wo0 - 1 + i;
        xr[i] = ((unsigned)wi < (unsigned)WIN)
                    ? x[(((size_t)(n * CIN + c) * HIN + hi) * WIN + wi) * 50 + tt]
                    : 0.f;
      }
#pragma unroll
      for (int co = 0; co < COUT; ++co)
#pragma unroll
        for (int kw = 0; kw < KK; ++kw) {
          const float wv = w[((co * CIN + c) * KK + kh) * KK + kw];
#pragma unroll
          for (int wl = 0; wl < WT; ++wl)
            acc[co][wl] += xr[2 * wl + kw] * wv;
        }
    }
  }

  if (lane < 50) {
#pragma unroll
    for (int co = 0; co < COUT; ++co)
#pragma unroll
      for (int wl = 0; wl < WT; ++wl)
        lds[(co * TW + wave * WT + wl) * 51 + lane] = acc[co][wl];
  }
  __syncthreads();
  // ---- FIR = psp (commuted past conv): 2 threads/row ----
  {
    const int r = tid % NROW;
    const int part = tid / NROW;
    const int wol = r % TW;
    const bool act = (part < 2) && (group * TW + wol < WOUT);
    float xs[50];
    if (act) {
      if (part == 0) {
#pragma unroll
        for (int t = 0; t < 25; ++t) xs[t] = lds[r * 51 + t];
      } else {
#pragma unroll
        for (int t = 0; t < 50; ++t) xs[t] = lds[r * 51 + t];
      }
    }
    __syncthreads();
    if (act) {
      if (part == 0) {
#pragma unroll
        for (int t = 0; t < 25; ++t) {
          float a = 0.f;
#pragma unroll
          for (int k = 31; k >= 0; --k)
            if (t - k >= 0) a += xs[t - k] * pk.k[k];
          lds[r * 51 + t] = a;
        }
      } else {
#pragma unroll
        for (int t = 25; t < 50; ++t) {
          float a = 0.f;
#pragma unroll
          for (int k = 31; k >= 0; --k)
            if (t - k >= 0) a += xs[t - k] * pk.k[k];
          lds[r * 51 + t] = a;
        }
      }
    }
  }
  __syncthreads();
  // spike along t, one thread per output row, direct float2 store from regs
  if (tid < NROW) {
    const int co = tid / TW;
    const int wol = tid - co * TW;
    const int wo = group * TW + wol;
    if (wo < WOUT) {
      float* orow = s + (((size_t)(n * COUT + co) * HOUT + ho) * WOUT + wo) * 50;
      float buf[16];
#pragma unroll
      for (int j = 0; j < 16; ++j) buf[j] = 0.f;
      float prev = 0.f;
#pragma unroll
      for (int t = 0; t < 50; ++t) {
        float v = lds[tid * 51 + t] + buf[t & 15];
        buf[t & 15] = 0.f;
        float sp = 0.f;
        if (v >= THETA) {
          sp = 1.f;
#pragma unroll
          for (int j = 0; j < 16; ++j) buf[(t + 1 + j) & 15] += rk.k[j];
        }
        if (t & 1) *(float2*)(orow + t - 1) = make_float2(prev, sp);
        else prev = sp;
      }
    }
  }
}

// ====== fc + psp(commuted) + final spike (verified) ======
__global__ __launch_bounds__(512)
void fc_fir_spike_kernel(const float* __restrict__ w, const float* __restrict__ s,
                         float* __restrict__ out, K32 pk, K16 rk) {
  __shared__ float lds[8 * 51];
  const int tid = threadIdx.x;
  const int wave = tid >> 6, lane = tid & 63;
  const int o = wave & 1, n = wave >> 1;
  const int tt = lane < 50 ? lane : 49;
  const float* wrow = w + (size_t)o * 2048;
  const float* ub = s + (size_t)n * 2048 * 50;
  float acc = 0.f;
#pragma unroll 32
  for (int i = 0; i < 2048; ++i) acc += wrow[i] * ub[(size_t)i * 50 + tt];
  if (lane < 50) lds[wave * 51 + lane] = acc;
  __syncthreads();
  // ---- FIR = psp6 (commuted past einsum): 2 threads/row, in place ----
  {
    const int r = tid & 7;
    const int part = tid >> 3;      // only part<2 active
    const bool act = part < 2;
    float xs[50];
    if (act) {
      if (part == 0) {
#pragma unroll
        for (int t = 0; t < 25; ++t) xs[t] = lds[r * 51 + t];
      } else {
#pragma unroll
        for (int t = 0; t < 50; ++t) xs[t] = lds[r * 51 + t];
      }
    }
    __syncthreads();
    if (act) {
      if (part == 0) {
#pragma unroll
        for (int t = 0; t < 25; ++t) {
          float a = 0.f;
#pragma unroll
          for (int k = 31; k >= 0; --k)
            if (t - k >= 0) a += xs[t - k] * pk.k[k];
          lds[r * 51 + t] = a;
        }
      } else {
#pragma unroll
        for (int t = 25; t < 50; ++t) {
          float a = 0.f;
#pragma unroll
          for (int k = 31; k >= 0; --k)
            if (t - k >= 0) a += xs[t - k] * pk.k[k];
          lds[r * 51 + t] = a;
        }
      }
    }
  }
  __syncthreads();
  if (tid < 8) {
    float buf[16];
#pragma unroll
    for (int j = 0; j < 16; ++j) buf[j] = 0.f;
#pragma unroll
    for (int t = 0; t < 50; ++t) {
      float v = lds[tid * 51 + t] + buf[t & 15];
      buf[t & 15] = 0.f;
      float sp = 0.f;
      if (v >= THETA) {
        sp = 1.f;
#pragma unroll
        for (int j = 0; j < 16; ++j) buf[(t + 1 + j) & 15] += rk.k[j];
      }
      out[tid * 50 + t] = sp;
    }
  }
}

extern "C" void kernel_launch(void* const* d_in, const int* in_sizes, int n_in,
                              void* d_out, int out_size, void* d_ws, size_t ws_size,
                              hipStream_t stream) {
  const float* xin = (const float*)d_in[0];  // [4,2,256,256,50] raw binary spikes
  const float* w1  = (const float*)d_in[1];  // [8,2,5,5]
  const float* w2  = (const float*)d_in[2];  // [16,8,3,3]
  const float* w3  = (const float*)d_in[3];  // [32,16,3,3]
  const float* wfc = (const float*)d_in[4];  // [2,32,8,8]
  float* out = (float*)d_out;                // [4,2,1,1,50]

  float* R0 = (float*)d_ws;                  // 26,214,400 floats
  float* R1 = R0 + 26214400;

  K32 pk;
  for (int k = 0; k < 32; ++k)
    pk.k[k] = (float)(((double)k / 10.0) * exp(1.0 - (double)k / 10.0));
  K16 rk;
  for (int j = 0; j < 16; ++j) {
    const double tr = (double)(j + 1);
    rk.k[j] = (float)(-2.0 * 10.0 * tr * exp(1.0 - tr));
  }

  // 1. FULLY FUSED L1: conv1(raw x)+psp1+spike1+psp2+pool1+spike2: xin -> R1 = s2
  conv_pps_kernel<2, 8, 5, 256, 256, 127, 127, 63, 63>
      <<<4 * 63 * 16, 256, 0, stream>>>(xin, w1, R1, pk, rk);
  // 2. MERGED L2: conv2+psp3+spike3+pool2+psp4+spike4: R1 -> R0 = s4 [4,16,16,16,50]
  conv_pps2_kernel<8, 16, 3, 4, 2, 63, 63, 32, 32, 16, 16>
      <<<4 * 16 * 8, 256, 0, stream>>>(R1, w2, R0, pk, rk);
  // 3. FUSED conv3+psp5+spike5: R0 -> R1 = s5 [4,32,8,8,50]
  conv_fir_spike_kernel<16, 32, 3, 1, 16, 16, 8, 8>
      <<<4 * 8 * 2, 256, 0, stream>>>(R0, w3, R1, pk, rk);
  // 4. FUSED fc+psp6+final spike: R1 -> out
  fc_fir_spike_kernel<<<1, 512, 0, stream>>>(wfc, R1, out, pk, rk);
}